// Round 5
// baseline (390.192 us; speedup 1.0000x reference)
//
#include <hip/hip_runtime.h>
#include <hip/hip_bf16.h>

typedef __hip_bfloat16 bf16;
typedef __attribute__((ext_vector_type(8))) short short8;
typedef __attribute__((ext_vector_type(4))) float f32x4;
typedef __attribute__((ext_vector_type(4))) unsigned int u32x4;

__device__ __forceinline__ float bfbits2f(unsigned short u) {
    return __uint_as_float(((unsigned int)u) << 16);
}
__device__ __forceinline__ unsigned short f2bfbits(float f) {
    union { float f; unsigned int u; } x;
    x.f = f;
    unsigned int r = x.u + 0x7FFFu + ((x.u >> 16) & 1u);
    return (unsigned short)(r >> 16);
}
// pack two fp32 -> two bf16 in one dword (RNE via HW cvt_pk)
__device__ __forceinline__ unsigned int cvtpk_bf16x2(float lo, float hi) {
    unsigned int w;
    asm("v_cvt_pk_bf16_f32 %0, %1, %2" : "=v"(w) : "v"(lo), "v"(hi));
    return w;
}
// async 16B global->LDS (wave-uniform LDS base; HW adds lane*16)
__device__ __forceinline__ void async_copy16(const void* g, void* l) {
    __builtin_amdgcn_global_load_lds(
        (const __attribute__((address_space(1))) void*)g,
        (__attribute__((address_space(3))) void*)l, 16, 0, 0);
}
// wave-level dtype sniff: true if the 64 dwords at p have bf16-plausible
// low halves (bf16 tensor), false for fp32 (low half = mantissa noise).
__device__ __forceinline__ bool sniff_bf16(const unsigned int* p, int lane) {
    unsigned int wd = p[lane];
    unsigned int e = (wd >> 7) & 0xFFu;
    return __popcll(__ballot(e >= 90u && e <= 150u)) > 40;
}

// ---------------------------------------------------------------------------
// prep: fused x-conversion (blocks 0..2047) + weight transpose/convert
// (blocks 2048..6143). Per-block inline dtype detection (no flags kernel).
// Wq pre-scaled by 0.125 * log2(e) so attention can use raw v_exp_f32 (2^x).
// ---------------------------------------------------------------------------
__global__ __launch_bounds__(256) void prep(
    const void* __restrict__ X, const void* __restrict__ W1,
    const void* __restrict__ W2, const void* __restrict__ W3,
    const void* __restrict__ W4, short* __restrict__ xb,
    short* __restrict__ O1, short* __restrict__ O2,
    short* __restrict__ O3, short* __restrict__ O4) {
    __shared__ float tbuf[32][33];
    const int bx = blockIdx.x;
    const int tid = threadIdx.x;
    const int lane = tid & 63;

    if (bx < 2048) {
        const bool isBf = sniff_bf16((const unsigned int*)X, lane);
        const int i = (bx * 256 + tid) * 8;
        if (isBf) {
            *(short8*)&xb[i] = *(const short8*)((const short*)X + i);
        } else {
            const float* xf = (const float*)X + i;
            float4 a = *(const float4*)xf;
            float4 b = *(const float4*)(xf + 4);
            short8 o;
            o[0] = (short)f2bfbits(a.x); o[1] = (short)f2bfbits(a.y);
            o[2] = (short)f2bfbits(a.z); o[3] = (short)f2bfbits(a.w);
            o[4] = (short)f2bfbits(b.x); o[5] = (short)f2bfbits(b.y);
            o[6] = (short)f2bfbits(b.z); o[7] = (short)f2bfbits(b.w);
            *(short8*)&xb[i] = o;
        }
    } else {
        const void* Ws[4] = {W1, W2, W3, W4};
        short* Os[4] = {O1, O2, O3, O4};
        const int t = bx - 2048;
        const int wsel = t >> 10;
        const int tile = t & 1023;
        const int bxt = tile & 31, byt = tile >> 5;
        const void* W = Ws[wsel];
        const bool isBf = sniff_bf16((const unsigned int*)W, lane);
        // 0.125 * log2(e): scores come out pre-scaled for exp2-based softmax
        const float scale = (wsel == 0) ? 0.18033688f : 1.0f;
        short* O = Os[wsel];

        const int tx = tid & 31, ty = tid >> 5;
        const int gx = bxt * 32 + tx;
#pragma unroll
        for (int i = 0; i < 4; i++) {
            const int gy = byt * 32 + ty + i * 8;
            float v = isBf
                ? bfbits2f(((const unsigned short*)W)[(size_t)gy * 1024 + gx])
                : ((const float*)W)[(size_t)gy * 1024 + gx];
            tbuf[ty + i * 8][tx] = v * scale;
        }
        __syncthreads();
#pragma unroll
        for (int i = 0; i < 4; i++) {
            const int orow = bxt * 32 + ty + i * 8;
            const int ocol = byt * 32 + tx;
            O[(size_t)orow * 1024 + ocol] = (short)f2bfbits(tbuf[tx][ty + i * 8]);
        }
    }
}

// ---------------------------------------------------------------------------
// V pre-transpose with pi-interleave (pi(k)=2*(k&15)+(k>>4) per 32-block).
// pi matches the in-register P packing of the swapped-QK^T attention: packed
// A-fragment slot p = quad*8+e holds key kappa(p), and pi(kappa(p)) == p.
// ---------------------------------------------------------------------------
__global__ __launch_bounds__(256) void transpose_v(const short* __restrict__ qkv,
                                                   short* __restrict__ VtG) {
    __shared__ short t[32][33];
    const int tx = threadIdx.x & 31, ty = threadIdx.x >> 5;
    const int b = blockIdx.z >> 4, h = blockIdx.z & 15;
    const int l0 = blockIdx.x * 32, d0 = blockIdx.y * 32;
#pragma unroll
    for (int i = 0; i < 4; i++) {
        const int l = l0 + ty + i * 8;
        t[ty + i * 8][tx] =
            qkv[(size_t)(b * 2048 + l) * 3072 + 2048 + h * 64 + d0 + tx];
    }
    __syncthreads();
    const int ptx = 2 * (tx & 15) + (tx >> 4);
#pragma unroll
    for (int i = 0; i < 4; i++) {
        const int d = d0 + ty + i * 8;
        VtG[((size_t)(b * 16 + h) * 64 + d) * 2048 + l0 + ptx] = t[tx][ty + i * 8];
    }
}

// ---------------------------------------------------------------------------
// MFMA GEMM, single-barrier dbuf K-loop. xdet==nullptr -> bf16 out;
// else output dtype follows sniffed dtype of xdet (the original x tensor).
// T2 XOR swizzle via pre-swizzled global source (rule #21).
// ---------------------------------------------------------------------------
template <int BN>
__global__ __launch_bounds__(256) void gemm_async(const short* __restrict__ A,
                                                  const short* __restrict__ Bt,
                                                  void* __restrict__ C,
                                                  const unsigned int* __restrict__ xdet,
                                                  int M, int N, int K) {
    __shared__ short As[2][128 * 32];
    __shared__ short Bs[2][BN * 32];
    constexpr int NI = BN / 32;

    const int tid = threadIdx.x;
    const int lane = tid & 63;
    const int wv = __builtin_amdgcn_readfirstlane(tid >> 6);
    const int quad = lane >> 4, l16 = lane & 15;
    const int wr = wv >> 1, wc = wv & 1;
    const int m0 = blockIdx.y * 128, n0 = blockIdx.x * BN;

    const int gr = lane >> 2;                               // staged row in 16-row unit
    const int gc = ((lane & 3) ^ ((lane >> 3) & 3)) * 8;    // pre-swizzled source col

    const f32x4 zero = {0.f, 0.f, 0.f, 0.f};
    f32x4 acc[4][NI];
#pragma unroll
    for (int mi = 0; mi < 4; mi++)
#pragma unroll
        for (int ni = 0; ni < NI; ni++) acc[mi][ni] = zero;

    const short* aptr[2];
    const short* bptr[BN / 64];
#pragma unroll
    for (int t = 0; t < 2; t++)
        aptr[t] = A + (size_t)(m0 + t * 64 + wv * 16 + gr) * K + gc;
#pragma unroll
    for (int t = 0; t < BN / 64; t++)
        bptr[t] = Bt + (size_t)(n0 + t * 64 + wv * 16 + gr) * K + gc;

#pragma unroll
    for (int t = 0; t < 2; t++) async_copy16(aptr[t], &As[0][(t * 64 + wv * 16) * 32]);
#pragma unroll
    for (int t = 0; t < BN / 64; t++) async_copy16(bptr[t], &Bs[0][(t * 64 + wv * 16) * 32]);

    // read-side swizzled 16B slot (constant per lane): quad ^ ((row>>1)&3)
    const int ss = (quad ^ ((l16 >> 1) & 3)) * 8;

    for (int k0 = 0; k0 < K; k0 += 32) {
        const int cur = (k0 >> 5) & 1;
        __syncthreads();
        if (k0 + 32 < K) {
            const int nxt = cur ^ 1;
#pragma unroll
            for (int t = 0; t < 2; t++)
                async_copy16(aptr[t] + k0 + 32, &As[nxt][(t * 64 + wv * 16) * 32]);
#pragma unroll
            for (int t = 0; t < BN / 64; t++)
                async_copy16(bptr[t] + k0 + 32, &Bs[nxt][(t * 64 + wv * 16) * 32]);
        }

        short8 af[4], bfv[NI];
#pragma unroll
        for (int mi = 0; mi < 4; mi++)
            af[mi] = *(const short8*)&As[cur][(wr * 64 + mi * 16 + l16) * 32 + ss];
#pragma unroll
        for (int ni = 0; ni < NI; ni++)
            bfv[ni] = *(const short8*)&Bs[cur][(wc * (BN / 2) + ni * 16 + l16) * 32 + ss];
#pragma unroll
        for (int mi = 0; mi < 4; mi++)
#pragma unroll
            for (int ni = 0; ni < NI; ni++)
                acc[mi][ni] = __builtin_amdgcn_mfma_f32_16x16x32_bf16(
                    af[mi], bfv[ni], acc[mi][ni], 0, 0, 0);
    }

    bool outBf = true;
    if (xdet) outBf = sniff_bf16(xdet, lane);
    if (outBf) {
        unsigned short* Cb = (unsigned short*)C;
#pragma unroll
        for (int mi = 0; mi < 4; mi++)
#pragma unroll
            for (int ni = 0; ni < NI; ni++)
#pragma unroll
                for (int r = 0; r < 4; r++) {
                    const int row = m0 + wr * 64 + mi * 16 + quad * 4 + r;
                    const int col = n0 + wc * (BN / 2) + ni * 16 + l16;
                    Cb[(size_t)row * N + col] = f2bfbits(acc[mi][ni][r]);
                }
    } else {
        float* Cf = (float*)C;
#pragma unroll
        for (int mi = 0; mi < 4; mi++)
#pragma unroll
            for (int ni = 0; ni < NI; ni++)
#pragma unroll
                for (int r = 0; r < 4; r++) {
                    const int row = m0 + wr * 64 + mi * 16 + quad * 4 + r;
                    const int col = n0 + wc * (BN / 2) + ni * 16 + l16;
                    Cf[(size_t)row * N + col] = acc[mi][ni][r];
                }
    }
}

// ---------------------------------------------------------------------------
// MFMA flash attention v11: 128q x 64k steps, 8 waves (512 thr),
// (wvq 0..3, wvk 0..1); per-wave inner math identical to proven v9/v10
// (32q x 32k, swapped QK^T, in-register pi-packed P, dbuf global_load_lds
// staging w/ XOR swizzle). Halves block-step count (66 -> 33 per CU) at
// ~same per-step latency: the measured regime is serial-latency-bound
// (1560cyc/step vs ~600 pipe work), so fewer+fatter steps win.
// sb-loop unrolled x2 (static buffer indices), cvt_pk pack, ones-MFMA l,
// setprio around PV. Waves 0-3 stage K, 4-7 stage V (2x copy16 each).
// Epilogue O-exchange aliases the dead K/V buffers ([128][68] f32).
// slots: [0,32) S=4 qbb=15-(slot>>2); [32,40) S=2 qbb=7-((slot-32)>>1);
// [40,44) S=1 qbb=43-slot. ns = 2*qbb+2 64-key steps.
// ---------------------------------------------------------------------------
__global__ __launch_bounds__(512, 6) void attn_mfma11(
    const short* __restrict__ qkv, const short* __restrict__ VtG,
    short* __restrict__ Yg, short* __restrict__ Opart, float* __restrict__ ml) {
    __shared__ char smem[34816 + 1024];
    short* KVs = (short*)smem;            // [2 buf][2 kv][64*64] = 32768 B
    float* scrf = (float*)smem;           // epilogue alias: [128][68] f32
    float* lred = (float*)(smem + 34816); // [2][128]

    const int tid = threadIdx.x;
    const int lane = tid & 63;
    const int wv = __builtin_amdgcn_readfirstlane(tid >> 6);  // 0..7
    const int wvq = wv >> 1, wvk = wv & 1;
    const int quad = lane >> 4, l16 = lane & 15;
    const int bh = blockIdx.x;  // bh fastest: long slots dispatch first
    const int b = bh >> 4, h = bh & 15;

    int qbb, seg, S;
    const int slot = blockIdx.y;
    if (slot < 32)      { qbb = 15 - (slot >> 2); seg = slot & 3; S = 4; }
    else if (slot < 40) { const int t2 = slot - 32; qbb = 7 - (t2 >> 1); seg = t2 & 1; S = 2; }
    else                { qbb = 43 - slot; seg = 0; S = 1; }

    const int ns = 2 * qbb + 2;  // 64-key steps for this 128q block
    const int sb0 = seg * ns / S;
    const int sb1 = (seg + 1) * ns / S;

    // staging: waves 0-3 stage K (units 0-7), waves 4-7 stage V (units 0-7).
    // unit u covers rows u*8..u*8+7 (128B each); lane -> row u*8+(lane>>3),
    // phys slot lane&7; source col pre-swizzled (lane&7)^(row&7).
    const int rr = lane >> 3;
    const int scol = ((lane & 7) ^ rr) * 8;
    const bool stK = (wv < 4);
    const int su = (wv & 3) * 2;

    const short* sptr[2];
    short* sdst[2];
#pragma unroll
    for (int i = 0; i < 2; i++) {
        const int u = su + i;
        if (stK) {
            sptr[i] = qkv + (size_t)(b * 2048 + sb0 * 64 + u * 8 + rr) * 3072 + 1024 +
                      h * 64 + scol;
            sdst[i] = KVs + (u * 8) * 64;
        } else {
            sptr[i] = VtG + ((size_t)bh * 64 + u * 8 + rr) * 2048 + sb0 * 64 + scol;
            sdst[i] = KVs + 4096 + (u * 8) * 64;
        }
    }
    const size_t sadv = stK ? (size_t)64 * 3072 : (size_t)64;

    constexpr int BUFS = 2 * 64 * 64;  // shorts per buffer (K+V)
    auto STAGE = [&](int bufi) {
#pragma unroll
        for (int i = 0; i < 2; i++) {
            async_copy16(sptr[i], sdst[i] + bufi * BUFS);
            sptr[i] += sadv;
        }
    };
    STAGE(0);  // K/V(sb0) -> buf0

    // ---- Q -> regs (this wave's 32 q rows) ----
    short8 qf[2][2];
    {
        const short* qbase = qkv +
            (size_t)(b * 2048 + qbb * 128 + wvq * 32 + l16) * 3072 + h * 64 + quad * 8;
#pragma unroll
        for (int qt = 0; qt < 2; qt++)
#pragma unroll
            for (int hf = 0; hf < 2; hf++)
                qf[qt][hf] = *(const short8*)(qbase + qt * 16 * 3072 + hf * 32);
    }

    // read-side swizzled slot (constant per lane): quad ^ (row&7), row&7=l16&7
    const int sl = (quad ^ (l16 & 7)) * 8;

    const f32x4 minit = {-17.3123405f, -17.3123405f, -17.3123405f, -17.3123405f};
    const short8 vone = {(short)0x3F80, (short)0x3F80, (short)0x3F80, (short)0x3F80,
                         (short)0x3F80, (short)0x3F80, (short)0x3F80, (short)0x3F80};
    f32x4 O[2][4];
#pragma unroll
    for (int qt = 0; qt < 2; qt++)
#pragma unroll
        for (int dt = 0; dt < 4; dt++) O[qt][dt] = {0.f, 0.f, 0.f, 0.f};
    f32x4 lacc[2] = {{0.f, 0.f, 0.f, 0.f}, {0.f, 0.f, 0.f, 0.f}};

    const int qmin = qbb * 128 + wvq * 32;   // wave's lowest q row
    const int keyoff = wvk * 32 + quad * 4;  // key offset within 64-step

    auto STEP = [&](int sb, int cur, bool pf) {
        __syncthreads();  // drains stage(cur) [vmcnt(0)] + waves done with other buf
        if (pf) STAGE(cur ^ 1);
        const short* Kc = KVs + cur * BUFS;
        const short* Vc = KVs + cur * BUFS + 4096;

        short8 kf[2][2], vf[4];
#pragma unroll
        for (int kt = 0; kt < 2; kt++)
#pragma unroll
            for (int hf = 0; hf < 2; hf++)
                kf[kt][hf] = *(const short8*)
                    &Kc[(wvk * 32 + kt * 16 + l16) * 64 + (sl ^ (hf << 5))];
#pragma unroll
        for (int dt = 0; dt < 4; dt++)
            vf[dt] = *(const short8*)
                &Vc[(dt * 16 + l16) * 64 + (sl ^ (wvk << 5))];

        const bool needmask = (sb * 64 + 63 > qmin);  // wave-uniform
#pragma unroll
        for (int qt = 0; qt < 2; qt++) {
            f32x4 sA = __builtin_amdgcn_mfma_f32_16x16x32_bf16(kf[0][0], qf[qt][0], minit, 0, 0, 0);
            sA = __builtin_amdgcn_mfma_f32_16x16x32_bf16(kf[0][1], qf[qt][1], sA, 0, 0, 0);
            f32x4 sB = __builtin_amdgcn_mfma_f32_16x16x32_bf16(kf[1][0], qf[qt][0], minit, 0, 0, 0);
            sB = __builtin_amdgcn_mfma_f32_16x16x32_bf16(kf[1][1], qf[qt][1], sB, 0, 0, 0);
            if (needmask) {  // causal
                const int qcol = qmin + qt * 16 + l16;
                const int key0 = sb * 64 + keyoff;
#pragma unroll
                for (int r = 0; r < 4; r++) {
                    if (key0 + r > qcol) sA[r] = -1e30f;
                    if (key0 + 16 + r > qcol) sB[r] = -1e30f;
                }
            }
            union { u32x4 u; short8 s; } pa;
#pragma unroll
            for (int t = 0; t < 4; t++) {
                sA[t] = __builtin_amdgcn_exp2f(sA[t]);
                sB[t] = __builtin_amdgcn_exp2f(sB[t]);
                pa.u[t] = cvtpk_bf16x2(sA[t], sB[t]);
            }
            __builtin_amdgcn_s_setprio(1);
#pragma unroll
            for (int dt = 0; dt < 4; dt++)
                O[qt][dt] = __builtin_amdgcn_mfma_f32_16x16x32_bf16(
                    pa.s, vf[dt], O[qt][dt], 0, 0, 0);
            lacc[qt] = __builtin_amdgcn_mfma_f32_16x16x32_bf16(
                pa.s, vone, lacc[qt], 0, 0, 0);
            __builtin_amdgcn_s_setprio(0);
        }
    };

    // ---- main loop, unrolled x2 (static buffer indices) ----
    const int n = sb1 - sb0;
    int i = 0;
    for (; i + 2 <= n; i += 2) {
        STEP(sb0 + i, 0, true);
        STEP(sb0 + i + 1, 1, i + 2 < n);
    }
    if (i < n) STEP(sb0 + i, 0, false);

    // ---- publish l (lacc rowsums; all cols equal -> take l16==0 lanes) ----
    if (l16 == 0) {
#pragma unroll
        for (int qt = 0; qt < 2; qt++)
#pragma unroll
            for (int r = 0; r < 4; r++)
                lred[wvk * 128 + wvq * 32 + qt * 16 + quad * 4 + r] = lacc[qt][r];
    }

    __syncthreads();  // loop + lred done -> K/V dead, scr safe
    if (wvk == 1) {
#pragma unroll
        for (int qt = 0; qt < 2; qt++)
#pragma unroll
            for (int dt = 0; dt < 4; dt++)
#pragma unroll
                for (int r = 0; r < 4; r++)
                    scrf[(wvq * 32 + qt * 16 + quad * 4 + r) * 68 + dt * 16 + l16] =
                        O[qt][dt][r];
    }
    __syncthreads();

    if (wvk == 0) {
#pragma unroll
        for (int qt = 0; qt < 2; qt++)
#pragma unroll
            for (int dt = 0; dt < 4; dt++)
#pragma unroll
                for (int r = 0; r < 4; r++)
                    O[qt][dt][r] += scrf[(wvq * 32 + qt * 16 + quad * 4 + r) * 68 +
                                         dt * 16 + l16];
        if (S == 1) {
#pragma unroll
            for (int qt = 0; qt < 2; qt++)
#pragma unroll
                for (int r = 0; r < 4; r++) {
                    const int q = wvq * 32 + qt * 16 + quad * 4 + r;
                    const float inv = 1.f / (lred[q] + lred[128 + q]);
#pragma unroll
                    for (int dt = 0; dt < 4; dt++)
                        Yg[(size_t)(b * 2048 + qbb * 128 + q) * 1024 + h * 64 +
                           dt * 16 + l16] = (short)f2bfbits(O[qt][dt][r] * inv);
                }
        } else {
            const int qidx = qbb - 4;  // 0..11
            const int base = ((seg * 32 + bh) * 12 + qidx) * 128;
#pragma unroll
            for (int qt = 0; qt < 2; qt++)
#pragma unroll
                for (int r = 0; r < 4; r++) {
                    const int q = wvq * 32 + qt * 16 + quad * 4 + r;
#pragma unroll
                    for (int dt = 0; dt < 4; dt++)
                        Opart[(size_t)(base + q) * 64 + dt * 16 + l16] =
                            (short)f2bfbits(O[qt][dt][r]);  // unnormalized
                    if (l16 == 0) ml[base + q] = lred[q] + lred[128 + q];
                }
        }
    }
}

// ---------------------------------------------------------------------------
// Combine split-K partials: S=4 for qbb>=8, S=2 for qbb in [4,8).
// grid.x = 24: qbb = 4 + (x>>1), 64-row half = x&1.
// ---------------------------------------------------------------------------
__global__ __launch_bounds__(256) void attn_combine11(
    const short* __restrict__ Opart, const float* __restrict__ ml,
    short* __restrict__ Yg) {
    const int x = blockIdx.x;
    const int qbb = 4 + (x >> 1);
    const int half = x & 1;
    const int bh = blockIdx.y;
    const int b = bh >> 4, h = bh & 15;
    const int S = (qbb >= 8) ? 4 : 2;
    const int qidx = qbb - 4;
    const int tid = threadIdx.x;
    const int q = (tid >> 2) + half * 64;  // row within 128q block
    const int d0 = (tid & 3) * 16;

    float a0[8] = {}, a1[8] = {};
    float lsum = 0.f;
    for (int s = 0; s < S; s++) {
        const int idx = ((s * 32 + bh) * 12 + qidx) * 128 + q;
        lsum += ml[idx];
        const short* p = Opart + (size_t)idx * 64 + d0;
        short8 x0 = *(const short8*)p;
        short8 x1 = *(const short8*)(p + 8);
#pragma unroll
        for (int t = 0; t < 8; t++) {
            a0[t] += bfbits2f((unsigned short)x0[t]);
            a1[t] += bfbits2f((unsigned short)x1[t]);
        }
    }
    const float inv = 1.f / lsum;
    short8 o0, o1;
#pragma unroll
    for (int t = 0; t < 8; t++) {
        o0[t] = (short)f2bfbits(a0[t] * inv);
        o1[t] = (short)f2bfbits(a1[t] * inv);
    }
    short* yp = Yg + (size_t)(b * 2048 + qbb * 128 + q) * 1024 + h * 64 + d0;
    *(short8*)yp = o0;
    *(short8*)(yp + 8) = o1;
}

// ---------------------------------------------------------------------------
extern "C" void kernel_launch(void* const* d_in, const int* in_sizes, int n_in,
                              void* d_out, int out_size, void* d_ws, size_t ws_size,
                              hipStream_t stream) {
    const int M = 2 * 2048;
    const int D = 1024;

    // ws: xb/y 8M | WT 8M | qkv 24M | VtG 8M | Opart 24M | ml 0.75M  (~73 MiB)
    char* w = (char*)d_ws;
    short* xb  = (short*)w;
    short* WqT = (short*)(w + (8u << 20));
    short* WkT = WqT + (1u << 20);
    short* WvT = WkT + (1u << 20);
    short* WoT = WvT + (1u << 20);
    short* qkv = WoT + (1u << 20);            // [4096][3072]
    short* VtG = qkv + (size_t)M * 3072;      // [32*64][2048] pi-interleaved
    short* Opart = VtG + (size_t)2048 * 2048; // [4][32][12][128][64] bf16
    float* mlp = (float*)(Opart + (size_t)4 * 32 * 12 * 128 * 64);
    short* y = xb;  // alias: xb dead after QKV GEMM

    prep<<<6144, 256, 0, stream>>>(d_in[0], d_in[1], d_in[2], d_in[3], d_in[4],
                                   xb, WqT, WkT, WvT, WoT);

    gemm_async<128><<<dim3(3072 / 128, M / 128), 256, 0, stream>>>(
        xb, WqT, qkv, nullptr, M, 3072, D);

    transpose_v<<<dim3(64, 2, 32), 256, 0, stream>>>(qkv, VtG);

    attn_mfma11<<<dim3(32, 44), 512, 0, stream>>>(qkv, VtG, y, Opart, mlp);
    attn_combine11<<<dim3(24, 32), 256, 0, stream>>>(Opart, mlp, y);

    gemm_async<64><<<dim3(D / 64, M / 128), 256, 0, stream>>>(
        y, WoT, d_out, (const unsigned int*)d_in[0], M, D, D);
}

// Round 7
// 180.826 us; speedup vs baseline: 2.1578x; 2.1578x over previous
//
#include <hip/hip_runtime.h>
#include <hip/hip_bf16.h>

typedef __hip_bfloat16 bf16;
typedef __attribute__((ext_vector_type(8))) short short8;
typedef __attribute__((ext_vector_type(4))) float f32x4;
typedef __attribute__((ext_vector_type(4))) unsigned int u32x4;

__device__ __forceinline__ float bfbits2f(unsigned short u) {
    return __uint_as_float(((unsigned int)u) << 16);
}
__device__ __forceinline__ unsigned short f2bfbits(float f) {
    union { float f; unsigned int u; } x;
    x.f = f;
    unsigned int r = x.u + 0x7FFFu + ((x.u >> 16) & 1u);
    return (unsigned short)(r >> 16);
}
// pack two fp32 -> two bf16 in one dword
__device__ __forceinline__ unsigned int pack_bf16x2(float lo, float hi) {
    unsigned int u0 = __float_as_uint(lo) + 0x8000u;
    unsigned int u1 = __float_as_uint(hi) + 0x8000u;
    return __builtin_amdgcn_perm(u1, u0, 0x07060302u);
}
// async 16B global->LDS (wave-uniform LDS base; HW adds lane*16)
__device__ __forceinline__ void async_copy16(const void* g, void* l) {
    __builtin_amdgcn_global_load_lds(
        (const __attribute__((address_space(1))) void*)g,
        (__attribute__((address_space(3))) void*)l, 16, 0, 0);
}
// wave-level dtype sniff: true if the 64 dwords at p have bf16-plausible
// low halves (bf16 tensor), false for fp32 (low half = mantissa noise).
__device__ __forceinline__ bool sniff_bf16(const unsigned int* p, int lane) {
    unsigned int wd = p[lane];
    unsigned int e = (wd >> 7) & 0xFFu;
    return __popcll(__ballot(e >= 90u && e <= 150u)) > 40;
}

// ---------------------------------------------------------------------------
// prep: fused x-conversion (blocks 0..2047) + weight transpose/convert
// (blocks 2048..6143). Per-block inline dtype detection (no flags kernel).
// Wq pre-scaled by 0.125 * log2(e) so attention can use raw v_exp_f32 (2^x).
// ---------------------------------------------------------------------------
__global__ __launch_bounds__(256) void prep(
    const void* __restrict__ X, const void* __restrict__ W1,
    const void* __restrict__ W2, const void* __restrict__ W3,
    const void* __restrict__ W4, short* __restrict__ xb,
    short* __restrict__ O1, short* __restrict__ O2,
    short* __restrict__ O3, short* __restrict__ O4) {
    __shared__ float tbuf[32][33];
    const int bx = blockIdx.x;
    const int tid = threadIdx.x;
    const int lane = tid & 63;

    if (bx < 2048) {
        const bool isBf = sniff_bf16((const unsigned int*)X, lane);
        const int i = (bx * 256 + tid) * 8;
        if (isBf) {
            *(short8*)&xb[i] = *(const short8*)((const short*)X + i);
        } else {
            const float* xf = (const float*)X + i;
            float4 a = *(const float4*)xf;
            float4 b = *(const float4*)(xf + 4);
            short8 o;
            o[0] = (short)f2bfbits(a.x); o[1] = (short)f2bfbits(a.y);
            o[2] = (short)f2bfbits(a.z); o[3] = (short)f2bfbits(a.w);
            o[4] = (short)f2bfbits(b.x); o[5] = (short)f2bfbits(b.y);
            o[6] = (short)f2bfbits(b.z); o[7] = (short)f2bfbits(b.w);
            *(short8*)&xb[i] = o;
        }
    } else {
        const void* Ws[4] = {W1, W2, W3, W4};
        short* Os[4] = {O1, O2, O3, O4};
        const int t = bx - 2048;
        const int wsel = t >> 10;
        const int tile = t & 1023;
        const int bxt = tile & 31, byt = tile >> 5;
        const void* W = Ws[wsel];
        const bool isBf = sniff_bf16((const unsigned int*)W, lane);
        // 0.125 * log2(e): scores come out pre-scaled for exp2-based softmax
        const float scale = (wsel == 0) ? 0.18033688f : 1.0f;
        short* O = Os[wsel];

        const int tx = tid & 31, ty = tid >> 5;
        const int gx = bxt * 32 + tx;
#pragma unroll
        for (int i = 0; i < 4; i++) {
            const int gy = byt * 32 + ty + i * 8;
            float v = isBf
                ? bfbits2f(((const unsigned short*)W)[(size_t)gy * 1024 + gx])
                : ((const float*)W)[(size_t)gy * 1024 + gx];
            tbuf[ty + i * 8][tx] = v * scale;
        }
        __syncthreads();
#pragma unroll
        for (int i = 0; i < 4; i++) {
            const int orow = bxt * 32 + ty + i * 8;
            const int ocol = byt * 32 + tx;
            O[(size_t)orow * 1024 + ocol] = (short)f2bfbits(tbuf[tx][ty + i * 8]);
        }
    }
}

// ---------------------------------------------------------------------------
// MFMA GEMM, single-barrier dbuf K-loop. xdet==nullptr -> bf16 out;
// else output dtype follows sniffed dtype of xdet (the original x tensor).
// T2 XOR swizzle via pre-swizzled global source (rule #21).
// VtGp != nullptr (QKV call only, BN=128): blocks with n0 >= 2048 are pure-V
// blocks; their epilogue writes pi-interleaved VtG directly (fused
// transpose_v) and skips the qkv V region entirely.
// pi(l) within 32-token blocks: pl = (l & ~31) + 2*(l&15) + ((l>>4)&1).
// ---------------------------------------------------------------------------
template <int BN>
__global__ __launch_bounds__(256) void gemm_async(const short* __restrict__ A,
                                                  const short* __restrict__ Bt,
                                                  void* __restrict__ C,
                                                  const unsigned int* __restrict__ xdet,
                                                  short* __restrict__ VtGp,
                                                  int M, int N, int K) {
    __shared__ short As[2][128 * 32];
    __shared__ short Bs[2][BN * 32];
    constexpr int NI = BN / 32;

    const int tid = threadIdx.x;
    const int lane = tid & 63;
    const int wv = __builtin_amdgcn_readfirstlane(tid >> 6);
    const int quad = lane >> 4, l16 = lane & 15;
    const int wr = wv >> 1, wc = wv & 1;
    const int m0 = blockIdx.y * 128, n0 = blockIdx.x * BN;

    const int gr = lane >> 2;                               // staged row in 16-row unit
    const int gc = ((lane & 3) ^ ((lane >> 3) & 3)) * 8;    // pre-swizzled source col

    const f32x4 zero = {0.f, 0.f, 0.f, 0.f};
    f32x4 acc[4][NI];
#pragma unroll
    for (int mi = 0; mi < 4; mi++)
#pragma unroll
        for (int ni = 0; ni < NI; ni++) acc[mi][ni] = zero;

    const short* aptr[2];
    const short* bptr[BN / 64];
#pragma unroll
    for (int t = 0; t < 2; t++)
        aptr[t] = A + (size_t)(m0 + t * 64 + wv * 16 + gr) * K + gc;
#pragma unroll
    for (int t = 0; t < BN / 64; t++)
        bptr[t] = Bt + (size_t)(n0 + t * 64 + wv * 16 + gr) * K + gc;

#pragma unroll
    for (int t = 0; t < 2; t++) async_copy16(aptr[t], &As[0][(t * 64 + wv * 16) * 32]);
#pragma unroll
    for (int t = 0; t < BN / 64; t++) async_copy16(bptr[t], &Bs[0][(t * 64 + wv * 16) * 32]);

    // read-side swizzled 16B slot (constant per lane): quad ^ ((row>>1)&3)
    const int ss = (quad ^ ((l16 >> 1) & 3)) * 8;

    for (int k0 = 0; k0 < K; k0 += 32) {
        const int cur = (k0 >> 5) & 1;
        __syncthreads();
        if (k0 + 32 < K) {
            const int nxt = cur ^ 1;
#pragma unroll
            for (int t = 0; t < 2; t++)
                async_copy16(aptr[t] + k0 + 32, &As[nxt][(t * 64 + wv * 16) * 32]);
#pragma unroll
            for (int t = 0; t < BN / 64; t++)
                async_copy16(bptr[t] + k0 + 32, &Bs[nxt][(t * 64 + wv * 16) * 32]);
        }

        short8 af[4], bfv[NI];
#pragma unroll
        for (int mi = 0; mi < 4; mi++)
            af[mi] = *(const short8*)&As[cur][(wr * 64 + mi * 16 + l16) * 32 + ss];
#pragma unroll
        for (int ni = 0; ni < NI; ni++)
            bfv[ni] = *(const short8*)&Bs[cur][(wc * (BN / 2) + ni * 16 + l16) * 32 + ss];
#pragma unroll
        for (int mi = 0; mi < 4; mi++)
#pragma unroll
            for (int ni = 0; ni < NI; ni++)
                acc[mi][ni] = __builtin_amdgcn_mfma_f32_16x16x32_bf16(
                    af[mi], bfv[ni], acc[mi][ni], 0, 0, 0);
    }

    if (VtGp != nullptr && n0 >= 2048) {
        // fused V transpose: scatter into pi-interleaved VtG (skip qkv)
        unsigned short* Vw = (unsigned short*)VtGp;
#pragma unroll
        for (int mi = 0; mi < 4; mi++)
#pragma unroll
            for (int ni = 0; ni < NI; ni++)
#pragma unroll
                for (int r = 0; r < 4; r++) {
                    const int row = m0 + wr * 64 + mi * 16 + quad * 4 + r;
                    const int col = n0 + wc * (BN / 2) + ni * 16 + l16;
                    const int vcol = col - 2048;
                    const int hh = vcol >> 6, d = vcol & 63;
                    const int bb = row >> 11, lloc = row & 2047;
                    const int pl = (lloc & ~31) + 2 * (lloc & 15) + ((lloc >> 4) & 1);
                    Vw[((size_t)(bb * 16 + hh) * 64 + d) * 2048 + pl] =
                        f2bfbits(acc[mi][ni][r]);
                }
        return;
    }

    bool outBf = true;
    if (xdet) outBf = sniff_bf16(xdet, lane);
    if (outBf) {
        unsigned short* Cb = (unsigned short*)C;
#pragma unroll
        for (int mi = 0; mi < 4; mi++)
#pragma unroll
            for (int ni = 0; ni < NI; ni++)
#pragma unroll
                for (int r = 0; r < 4; r++) {
                    const int row = m0 + wr * 64 + mi * 16 + quad * 4 + r;
                    const int col = n0 + wc * (BN / 2) + ni * 16 + l16;
                    Cb[(size_t)row * N + col] = f2bfbits(acc[mi][ni][r]);
                }
    } else {
        float* Cf = (float*)C;
#pragma unroll
        for (int mi = 0; mi < 4; mi++)
#pragma unroll
            for (int ni = 0; ni < NI; ni++)
#pragma unroll
                for (int r = 0; r < 4; r++) {
                    const int row = m0 + wr * 64 + mi * 16 + quad * 4 + r;
                    const int col = n0 + wc * (BN / 2) + ni * 16 + l16;
                    Cf[(size_t)row * N + col] = acc[mi][ni][r];
                }
    }
}

// ---------------------------------------------------------------------------
// MFMA flash attention v9 (verbatim from the verified R3 build).
// 4 waves = (wvq, wvk) in 2x2: wave computes q rows [wvq*32,+32) x keys
// [wvk*32,+32) of each 64-key step. K/V double-buffered in LDS via
// global_load_lds (pre-swizzled source, XOR slot swizzle on read). Swapped
// QK^T (s = mfma(K,Q)): q on l16, key on quad*4+r; exp'd P packs in-register
// via pack_bf16x2 into the PV A-fragment (pi-matched to VtG).
// Fixed-shift softmax -> key-split partials ADD: epilogue exchanges O across
// wvk pairs through a 4.3KB fp32 scratch (4 rounds) + lred for l.
// LDS: 16K + 16K + 4.4K + 0.5K = 37.6KB -> 4 blocks/CU.
// slot: [0,64) 4-way qb=31-(slot>>2); [64,80) 2-way qb=15-((slot-64)>>1);
// [80,88) single qb=87-slot.
// ---------------------------------------------------------------------------
__global__ __launch_bounds__(256) void attn_mfma9(
    const short* __restrict__ qkv, const short* __restrict__ VtG,
    short* __restrict__ Yg, short* __restrict__ Opart, float* __restrict__ ml) {
    __shared__ short Ks[2][64 * 64];   // [buf][key][64 d] swizzled, 8KB/buf
    __shared__ short Vt[2][64 * 64];   // [buf][d][64 key pi] swizzled
    __shared__ float scr[16][68];      // O-exchange scratch (one qt x wvq round)
    __shared__ float lred[2][64];      // [wvk][q]

    const int tid = threadIdx.x;
    const int lane = tid & 63;
    const int wv = __builtin_amdgcn_readfirstlane(tid >> 6);  // 0..3
    const int wvq = wv >> 1, wvk = wv & 1;
    const int quad = lane >> 4, l16 = lane & 15;
    const int bh = blockIdx.x;  // bh fastest: long slots dispatch first
    const int b = bh >> 4, h = bh & 15;

    int qb, seg, S;
    const int slot = blockIdx.y;
    if (slot < 64)      { qb = 31 - (slot >> 2); seg = slot & 3; S = 4; }
    else if (slot < 80) { const int t2 = slot - 64; qb = 15 - (t2 >> 1); seg = t2 & 1; S = 2; }
    else                { qb = 87 - slot; seg = 0; S = 1; }

    const int ns = qb + 1;  // 64-key blocks
    const int sb0 = seg * ns / S;
    const int sb1 = (seg + 1) * ns / S;

    // staging: unit u = wv*2+i covers rows u*8..u*8+7 (128B each).
    // lane -> row u*8 + (lane>>3), phys 16B slot lane&7; source col is
    // pre-swizzled: logical slot = (lane&7) ^ (row&7).
    const int rr = lane >> 3;                  // 0..7
    const int scol = ((lane & 7) ^ rr) * 8;    // swizzled source col (shorts)

    const short* kptr[2];
    const short* vptr[2];
    short* kdst[2];
    short* vdst[2];
#pragma unroll
    for (int i = 0; i < 2; i++) {
        const int u = wv * 2 + i;
        kptr[i] = qkv + (size_t)(b * 2048 + sb0 * 64 + u * 8 + rr) * 3072 + 1024 +
                  h * 64 + scol;
        kdst[i] = &Ks[0][(u * 8) * 64];
        vptr[i] = VtG + ((size_t)bh * 64 + u * 8 + rr) * 2048 + sb0 * 64 + scol;
        vdst[i] = &Vt[0][(u * 8) * 64];
    }
    const int bufoff = 64 * 64;  // shorts
    const int buf0 = sb0 & 1;

    // ---- prologue: K/V(sb0) -> buf0; Q -> regs (global, once) ----
#pragma unroll
    for (int i = 0; i < 2; i++) {
        async_copy16(kptr[i], kdst[i] + buf0 * bufoff);
        async_copy16(vptr[i], vdst[i] + buf0 * bufoff);
        kptr[i] += 64 * 3072;
        vptr[i] += 64;
    }
    short8 qf[2][2];
    {
        const short* qbase = qkv + (size_t)(b * 2048 + qb * 64 + wvq * 32 + l16) * 3072 +
                             h * 64 + quad * 8;
#pragma unroll
        for (int qt = 0; qt < 2; qt++)
#pragma unroll
            for (int hf = 0; hf < 2; hf++)
                qf[qt][hf] = *(const short8*)(qbase + qt * 16 * 3072 + hf * 32);
    }
    __syncthreads();  // drain prologue loads

    // read-side swizzled slot (constant per lane): quad ^ (row&7), row&7=l16&7
    const int sl = (quad ^ (l16 & 7)) * 8;

    const f32x4 minit = {-17.3123405f, -17.3123405f, -17.3123405f, -17.3123405f};
    f32x4 O[2][4];
#pragma unroll
    for (int qt = 0; qt < 2; qt++)
#pragma unroll
        for (int dt = 0; dt < 4; dt++) O[qt][dt] = {0.f, 0.f, 0.f, 0.f};
    float lp[2] = {0.f, 0.f};
    const int keyA0 = wvk * 32 + quad * 4;  // + r (kt=0); +16 for kt=1

    for (int sb = sb0; sb < sb1; sb++) {
        const int cur = sb & 1;
        if (sb != sb0) __syncthreads();  // drains prefetch into cur; frees other buf
        if (sb + 1 < sb1) {
            const int nxt = cur ^ 1;
#pragma unroll
            for (int i = 0; i < 2; i++) {
                async_copy16(kptr[i], kdst[i] + nxt * bufoff);
                async_copy16(vptr[i], vdst[i] + nxt * bufoff);
                kptr[i] += 64 * 3072;
                vptr[i] += 64;
            }
        }
        const short* Kc = &Ks[cur][0];
        const short* Vc = &Vt[cur][0];

        // ---- fragments: wave's own key half only (8 ds_read_b128) ----
        short8 kf[2][2], vf[4];
#pragma unroll
        for (int kt = 0; kt < 2; kt++)
#pragma unroll
            for (int hf = 0; hf < 2; hf++)
                kf[kt][hf] = *(const short8*)
                    &Kc[(wvk * 32 + kt * 16 + l16) * 64 + (sl ^ (hf << 5))];
#pragma unroll
        for (int dt = 0; dt < 4; dt++)
            vf[dt] = *(const short8*)
                &Vc[(dt * 16 + l16) * 64 + (sl ^ (wvk << 5))];

        // ---- per q-tile: S^T = K Q - 17.3 (in exp2 domain), exp, pack, PV ----
#pragma unroll
        for (int qt = 0; qt < 2; qt++) {
            f32x4 sA = __builtin_amdgcn_mfma_f32_16x16x32_bf16(kf[0][0], qf[qt][0], minit, 0, 0, 0);
            sA = __builtin_amdgcn_mfma_f32_16x16x32_bf16(kf[0][1], qf[qt][1], sA, 0, 0, 0);
            f32x4 sB = __builtin_amdgcn_mfma_f32_16x16x32_bf16(kf[1][0], qf[qt][0], minit, 0, 0, 0);
            sB = __builtin_amdgcn_mfma_f32_16x16x32_bf16(kf[1][1], qf[qt][1], sB, 0, 0, 0);
            if (sb == qb) {  // causal mask, diagonal block only
                const int qcol = wvq * 32 + qt * 16 + l16;
#pragma unroll
                for (int r = 0; r < 4; r++) {
                    if (keyA0 + r > qcol) sA[r] = -1e30f;
                    if (keyA0 + 16 + r > qcol) sB[r] = -1e30f;
                }
            }
            union { u32x4 u; short8 s; } pa;
#pragma unroll
            for (int t = 0; t < 4; t++) {
                sA[t] = __builtin_amdgcn_exp2f(sA[t]);
                sB[t] = __builtin_amdgcn_exp2f(sB[t]);
                lp[qt] += sA[t] + sB[t];
                pa.u[t] = pack_bf16x2(sA[t], sB[t]);
            }
#pragma unroll
            for (int dt = 0; dt < 4; dt++)
                O[qt][dt] = __builtin_amdgcn_mfma_f32_16x16x32_bf16(
                    pa.s, vf[dt], O[qt][dt], 0, 0, 0);
        }
    }

    // ---- l: reduce over quads (keys within wave), publish per wvk ----
#pragma unroll
    for (int qt = 0; qt < 2; qt++) {
        float v = lp[qt];
        v += __shfl_xor(v, 16);
        v += __shfl_xor(v, 32);
        if (quad == 0) lred[wvk][wvq * 32 + qt * 16 + l16] = v;
    }

    // ---- O exchange across wvk pairs: 4 rounds through 4.3KB scratch ----
#pragma unroll
    for (int g = 0; g < 2; g++)
#pragma unroll
        for (int qt = 0; qt < 2; qt++) {
            __syncthreads();
            if (wvq == g && wvk == 1) {
#pragma unroll
                for (int dt = 0; dt < 4; dt++)
#pragma unroll
                    for (int r = 0; r < 4; r++)
                        scr[quad * 4 + r][dt * 16 + l16] = O[qt][dt][r];
            }
            __syncthreads();
            if (wvq == g && wvk == 0) {
#pragma unroll
                for (int dt = 0; dt < 4; dt++)
#pragma unroll
                    for (int r = 0; r < 4; r++)
                        O[qt][dt][r] += scr[quad * 4 + r][dt * 16 + l16];
            }
        }

    // ---- output: wvk==0 waves own q rows [wvq*32, wvq*32+32) ----
    if (wvk == 0) {
        if (S == 1) {
#pragma unroll
            for (int qt = 0; qt < 2; qt++)
#pragma unroll
                for (int r = 0; r < 4; r++) {
                    const int q = wvq * 32 + qt * 16 + quad * 4 + r;
                    const float inv = 1.f / (lred[0][q] + lred[1][q]);
#pragma unroll
                    for (int dt = 0; dt < 4; dt++)
                        Yg[(size_t)(b * 2048 + qb * 64 + q) * 1024 + h * 64 +
                           dt * 16 + l16] = (short)f2bfbits(O[qt][dt][r] * inv);
                }
        } else {
            const int qidx = qb - 8;  // 0..23
            const int base = ((seg * 32 + bh) * 24 + qidx) * 64;
#pragma unroll
            for (int qt = 0; qt < 2; qt++)
#pragma unroll
                for (int r = 0; r < 4; r++) {
                    const int q = wvq * 32 + qt * 16 + quad * 4 + r;
#pragma unroll
                    for (int dt = 0; dt < 4; dt++)
                        Opart[(size_t)(base + q) * 64 + dt * 16 + l16] =
                            (short)f2bfbits(O[qt][dt][r]);  // unnormalized
                    if (l16 == 0) ml[base + q] = lred[0][q] + lred[1][q];
                }
        }
    }
}

// ---------------------------------------------------------------------------
// Combine split-K partials: S=4 for qb>=16, S=2 for qb in [8,16).
// ---------------------------------------------------------------------------
__global__ __launch_bounds__(256) void attn_combine6(
    const short* __restrict__ Opart, const float* __restrict__ ml,
    short* __restrict__ Yg) {
    const int qb = 8 + blockIdx.x;  // 8..31
    const int bh = blockIdx.y;
    const int b = bh >> 4, h = bh & 15;
    const int S = (qb >= 16) ? 4 : 2;
    const int qidx = qb - 8;
    const int tid = threadIdx.x;
    const int q = tid >> 2;
    const int d0 = (tid & 3) * 16;

    float a0[8] = {}, a1[8] = {};
    float lsum = 0.f;
    for (int s = 0; s < S; s++) {
        const int idx = ((s * 32 + bh) * 24 + qidx) * 64 + q;
        lsum += ml[idx];
        const short* p = Opart + (size_t)idx * 64 + d0;
        short8 x0 = *(const short8*)p;
        short8 x1 = *(const short8*)(p + 8);
#pragma unroll
        for (int t = 0; t < 8; t++) {
            a0[t] += bfbits2f((unsigned short)x0[t]);
            a1[t] += bfbits2f((unsigned short)x1[t]);
        }
    }
    const float inv = 1.f / lsum;
    short8 o0, o1;
#pragma unroll
    for (int t = 0; t < 8; t++) {
        o0[t] = (short)f2bfbits(a0[t] * inv);
        o1[t] = (short)f2bfbits(a1[t] * inv);
    }
    short* yp = Yg + (size_t)(b * 2048 + qb * 64 + q) * 1024 + h * 64 + d0;
    *(short8*)yp = o0;
    *(short8*)(yp + 8) = o1;
}

// ---------------------------------------------------------------------------
extern "C" void kernel_launch(void* const* d_in, const int* in_sizes, int n_in,
                              void* d_out, int out_size, void* d_ws, size_t ws_size,
                              hipStream_t stream) {
    const int M = 2 * 2048;
    const int D = 1024;

    // ws: xb/y 8M | WT 8M | qkv 24M | VtG 8M | Opart 24M | ml 0.75M  (~73 MiB)
    char* w = (char*)d_ws;
    short* xb  = (short*)w;
    short* WqT = (short*)(w + (8u << 20));
    short* WkT = WqT + (1u << 20);
    short* WvT = WkT + (1u << 20);
    short* WoT = WvT + (1u << 20);
    short* qkv = WoT + (1u << 20);            // [4096][3072] (V region unused)
    short* VtG = qkv + (size_t)M * 3072;      // [32*64][2048] pi-interleaved
    short* Opart = VtG + (size_t)2048 * 2048; // [4][32][24][64][64] bf16
    float* mlp = (float*)(Opart + (size_t)4 * 32 * 24 * 64 * 64);
    short* y = xb;  // alias: xb dead after QKV GEMM

    prep<<<6144, 256, 0, stream>>>(d_in[0], d_in[1], d_in[2], d_in[3], d_in[4],
                                   xb, WqT, WkT, WvT, WoT);

    // QKV GEMM with fused V transpose: V blocks (n0>=2048) write VtG directly.
    gemm_async<128><<<dim3(3072 / 128, M / 128), 256, 0, stream>>>(
        xb, WqT, qkv, nullptr, VtG, M, 3072, D);

    attn_mfma9<<<dim3(32, 88), 256, 0, stream>>>(qkv, VtG, y, Opart, mlp);
    attn_combine6<<<dim3(24, 32), 256, 0, stream>>>(Opart, mlp, y);

    gemm_async<64><<<dim3(D / 64, M / 128), 256, 0, stream>>>(
        y, WoT, d_out, (const unsigned int*)d_in[0], nullptr, M, D, D);
}

// Round 9
// 180.549 us; speedup vs baseline: 2.1611x; 1.0015x over previous
//
#include <hip/hip_runtime.h>
#include <hip/hip_bf16.h>

typedef __hip_bfloat16 bf16;
typedef __attribute__((ext_vector_type(8))) short short8;
typedef __attribute__((ext_vector_type(4))) float f32x4;
typedef __attribute__((ext_vector_type(4))) unsigned int u32x4;

__device__ __forceinline__ float bfbits2f(unsigned short u) {
    return __uint_as_float(((unsigned int)u) << 16);
}
__device__ __forceinline__ unsigned short f2bfbits(float f) {
    union { float f; unsigned int u; } x;
    x.f = f;
    unsigned int r = x.u + 0x7FFFu + ((x.u >> 16) & 1u);
    return (unsigned short)(r >> 16);
}
// pack two fp32 -> two bf16 in one dword
__device__ __forceinline__ unsigned int pack_bf16x2(float lo, float hi) {
    unsigned int u0 = __float_as_uint(lo) + 0x8000u;
    unsigned int u1 = __float_as_uint(hi) + 0x8000u;
    return __builtin_amdgcn_perm(u1, u0, 0x07060302u);
}
// async 16B global->LDS (wave-uniform LDS base; HW adds lane*16)
__device__ __forceinline__ void async_copy16(const void* g, void* l) {
    __builtin_amdgcn_global_load_lds(
        (const __attribute__((address_space(1))) void*)g,
        (__attribute__((address_space(3))) void*)l, 16, 0, 0);
}
// wave-level dtype sniff: true if the 64 dwords at p have bf16-plausible
// low halves (bf16 tensor), false for fp32 (low half = mantissa noise).
__device__ __forceinline__ bool sniff_bf16(const unsigned int* p, int lane) {
    unsigned int wd = p[lane];
    unsigned int e = (wd >> 7) & 0xFFu;
    return __popcll(__ballot(e >= 90u && e <= 150u)) > 40;
}

// ---------------------------------------------------------------------------
// prep: fused x-conversion (blocks 0..2047) + weight transpose/convert
// (blocks 2048..6143). Per-block inline dtype detection (no flags kernel).
// Wq pre-scaled by 0.125 * log2(e) so attention can use raw v_exp_f32 (2^x).
// ---------------------------------------------------------------------------
__global__ __launch_bounds__(256) void prep(
    const void* __restrict__ X, const void* __restrict__ W1,
    const void* __restrict__ W2, const void* __restrict__ W3,
    const void* __restrict__ W4, short* __restrict__ xb,
    short* __restrict__ O1, short* __restrict__ O2,
    short* __restrict__ O3, short* __restrict__ O4) {
    __shared__ float tbuf[32][33];
    const int bx = blockIdx.x;
    const int tid = threadIdx.x;
    const int lane = tid & 63;

    if (bx < 2048) {
        const bool isBf = sniff_bf16((const unsigned int*)X, lane);
        const int i = (bx * 256 + tid) * 8;
        if (isBf) {
            *(short8*)&xb[i] = *(const short8*)((const short*)X + i);
        } else {
            const float* xf = (const float*)X + i;
            float4 a = *(const float4*)xf;
            float4 b = *(const float4*)(xf + 4);
            short8 o;
            o[0] = (short)f2bfbits(a.x); o[1] = (short)f2bfbits(a.y);
            o[2] = (short)f2bfbits(a.z); o[3] = (short)f2bfbits(a.w);
            o[4] = (short)f2bfbits(b.x); o[5] = (short)f2bfbits(b.y);
            o[6] = (short)f2bfbits(b.z); o[7] = (short)f2bfbits(b.w);
            *(short8*)&xb[i] = o;
        }
    } else {
        const void* Ws[4] = {W1, W2, W3, W4};
        short* Os[4] = {O1, O2, O3, O4};
        const int t = bx - 2048;
        const int wsel = t >> 10;
        const int tile = t & 1023;
        const int bxt = tile & 31, byt = tile >> 5;
        const void* W = Ws[wsel];
        const bool isBf = sniff_bf16((const unsigned int*)W, lane);
        // 0.125 * log2(e): scores come out pre-scaled for exp2-based softmax
        const float scale = (wsel == 0) ? 0.18033688f : 1.0f;
        short* O = Os[wsel];

        const int tx = tid & 31, ty = tid >> 5;
        const int gx = bxt * 32 + tx;
#pragma unroll
        for (int i = 0; i < 4; i++) {
            const int gy = byt * 32 + ty + i * 8;
            float v = isBf
                ? bfbits2f(((const unsigned short*)W)[(size_t)gy * 1024 + gx])
                : ((const float*)W)[(size_t)gy * 1024 + gx];
            tbuf[ty + i * 8][tx] = v * scale;
        }
        __syncthreads();
#pragma unroll
        for (int i = 0; i < 4; i++) {
            const int orow = bxt * 32 + ty + i * 8;
            const int ocol = byt * 32 + tx;
            O[(size_t)orow * 1024 + ocol] = (short)f2bfbits(tbuf[tx][ty + i * 8]);
        }
    }
}

// ---------------------------------------------------------------------------
// MFMA GEMM, single-barrier dbuf K-loop. xdet==nullptr -> bf16 out;
// else output dtype follows sniffed dtype of xdet (the original x tensor).
// T2 XOR swizzle via pre-swizzled global source (rule #21).
// VtGp != nullptr (QKV call only, BN=128): blocks with n0 >= 2048 are pure-V
// blocks; their epilogue writes pi-interleaved VtG directly (fused
// transpose_v) and skips the qkv V region entirely.
// pi(l) within 32-token blocks: pl = (l & ~31) + 2*(l&15) + ((l>>4)&1).
// ---------------------------------------------------------------------------
template <int BN>
__global__ __launch_bounds__(256) void gemm_async(const short* __restrict__ A,
                                                  const short* __restrict__ Bt,
                                                  void* __restrict__ C,
                                                  const unsigned int* __restrict__ xdet,
                                                  short* __restrict__ VtGp,
                                                  int M, int N, int K) {
    __shared__ short As[2][128 * 32];
    __shared__ short Bs[2][BN * 32];
    constexpr int NI = BN / 32;

    const int tid = threadIdx.x;
    const int lane = tid & 63;
    const int wv = __builtin_amdgcn_readfirstlane(tid >> 6);
    const int quad = lane >> 4, l16 = lane & 15;
    const int wr = wv >> 1, wc = wv & 1;
    const int m0 = blockIdx.y * 128, n0 = blockIdx.x * BN;

    const int gr = lane >> 2;                               // staged row in 16-row unit
    const int gc = ((lane & 3) ^ ((lane >> 3) & 3)) * 8;    // pre-swizzled source col

    const f32x4 zero = {0.f, 0.f, 0.f, 0.f};
    f32x4 acc[4][NI];
#pragma unroll
    for (int mi = 0; mi < 4; mi++)
#pragma unroll
        for (int ni = 0; ni < NI; ni++) acc[mi][ni] = zero;

    const short* aptr[2];
    const short* bptr[BN / 64];
#pragma unroll
    for (int t = 0; t < 2; t++)
        aptr[t] = A + (size_t)(m0 + t * 64 + wv * 16 + gr) * K + gc;
#pragma unroll
    for (int t = 0; t < BN / 64; t++)
        bptr[t] = Bt + (size_t)(n0 + t * 64 + wv * 16 + gr) * K + gc;

#pragma unroll
    for (int t = 0; t < 2; t++) async_copy16(aptr[t], &As[0][(t * 64 + wv * 16) * 32]);
#pragma unroll
    for (int t = 0; t < BN / 64; t++) async_copy16(bptr[t], &Bs[0][(t * 64 + wv * 16) * 32]);

    // read-side swizzled 16B slot (constant per lane): quad ^ ((row>>1)&3)
    const int ss = (quad ^ ((l16 >> 1) & 3)) * 8;

    for (int k0 = 0; k0 < K; k0 += 32) {
        const int cur = (k0 >> 5) & 1;
        __syncthreads();
        if (k0 + 32 < K) {
            const int nxt = cur ^ 1;
#pragma unroll
            for (int t = 0; t < 2; t++)
                async_copy16(aptr[t] + k0 + 32, &As[nxt][(t * 64 + wv * 16) * 32]);
#pragma unroll
            for (int t = 0; t < BN / 64; t++)
                async_copy16(bptr[t] + k0 + 32, &Bs[nxt][(t * 64 + wv * 16) * 32]);
        }

        short8 af[4], bfv[NI];
#pragma unroll
        for (int mi = 0; mi < 4; mi++)
            af[mi] = *(const short8*)&As[cur][(wr * 64 + mi * 16 + l16) * 32 + ss];
#pragma unroll
        for (int ni = 0; ni < NI; ni++)
            bfv[ni] = *(const short8*)&Bs[cur][(wc * (BN / 2) + ni * 16 + l16) * 32 + ss];
#pragma unroll
        for (int mi = 0; mi < 4; mi++)
#pragma unroll
            for (int ni = 0; ni < NI; ni++)
                acc[mi][ni] = __builtin_amdgcn_mfma_f32_16x16x32_bf16(
                    af[mi], bfv[ni], acc[mi][ni], 0, 0, 0);
    }

    if (VtGp != nullptr && n0 >= 2048) {
        // fused V transpose: scatter into pi-interleaved VtG (skip qkv)
        unsigned short* Vw = (unsigned short*)VtGp;
#pragma unroll
        for (int mi = 0; mi < 4; mi++)
#pragma unroll
            for (int ni = 0; ni < NI; ni++)
#pragma unroll
                for (int r = 0; r < 4; r++) {
                    const int row = m0 + wr * 64 + mi * 16 + quad * 4 + r;
                    const int col = n0 + wc * (BN / 2) + ni * 16 + l16;
                    const int vcol = col - 2048;
                    const int hh = vcol >> 6, d = vcol & 63;
                    const int bb = row >> 11, lloc = row & 2047;
                    const int pl = (lloc & ~31) + 2 * (lloc & 15) + ((lloc >> 4) & 1);
                    Vw[((size_t)(bb * 16 + hh) * 64 + d) * 2048 + pl] =
                        f2bfbits(acc[mi][ni][r]);
                }
        return;
    }

    bool outBf = true;
    if (xdet) outBf = sniff_bf16(xdet, lane);
    if (outBf) {
        unsigned short* Cb = (unsigned short*)C;
#pragma unroll
        for (int mi = 0; mi < 4; mi++)
#pragma unroll
            for (int ni = 0; ni < NI; ni++)
#pragma unroll
                for (int r = 0; r < 4; r++) {
                    const int row = m0 + wr * 64 + mi * 16 + quad * 4 + r;
                    const int col = n0 + wc * (BN / 2) + ni * 16 + l16;
                    Cb[(size_t)row * N + col] = f2bfbits(acc[mi][ni][r]);
                }
    } else {
        float* Cf = (float*)C;
#pragma unroll
        for (int mi = 0; mi < 4; mi++)
#pragma unroll
            for (int ni = 0; ni < NI; ni++)
#pragma unroll
                for (int r = 0; r < 4; r++) {
                    const int row = m0 + wr * 64 + mi * 16 + quad * 4 + r;
                    const int col = n0 + wc * (BN / 2) + ni * 16 + l16;
                    Cf[(size_t)row * N + col] = acc[mi][ni][r];
                }
    }
}

// ---------------------------------------------------------------------------
// MFMA flash attention v12: 128q x 64k block-steps, 4 waves (256 thr).
// Wave wv owns q rows [wv*32, +32) and the FULL 64-key range of each step
// (chunk c=0,1 of 32 keys plays v9's wvk role -- identical pi-packed P->PV
// path, identical staging loop, identical __syncthreads dbuf protocol).
// vs v9: halves block-step count (16896 -> 8704), halves staging traffic
// (64-key tile reused by 128 q rows), and removes the cross-wave O-exchange
// and lred entirely (l is wave-local). LDS ~33KB -> 4 blocks/CU;
// __launch_bounds__(256,4) caps VGPR at 128 (~115 needed; R5 spill lesson).
// slots: [0,32) S=4 qbb=15-(slot>>2); [32,40) S=2 qbb=7-((slot-32)>>1);
// [40,44) S=1 qbb=43-slot. ns = 2*qbb+2 64-key steps.
// ---------------------------------------------------------------------------
__global__ __launch_bounds__(256, 4) void attn_mfma12(
    const short* __restrict__ qkv, const short* __restrict__ VtG,
    short* __restrict__ Yg, short* __restrict__ Opart, float* __restrict__ ml) {
    __shared__ short Ks[2][64 * 64];   // [buf][key][64 d] swizzled, 8KB/buf
    __shared__ short Vt[2][64 * 64];   // [buf][d][64 key pi] swizzled
    __shared__ float lred[4][32];      // [wave][q] wave-local l transpose

    const int tid = threadIdx.x;
    const int lane = tid & 63;
    const int wv = __builtin_amdgcn_readfirstlane(tid >> 6);  // 0..3 = q strip
    const int quad = lane >> 4, l16 = lane & 15;
    const int bh = blockIdx.x;  // bh fastest: long slots dispatch first
    const int b = bh >> 4, h = bh & 15;

    int qbb, seg, S;
    const int slot = blockIdx.y;
    if (slot < 32)      { qbb = 15 - (slot >> 2); seg = slot & 3; S = 4; }
    else if (slot < 40) { const int t2 = slot - 32; qbb = 7 - (t2 >> 1); seg = t2 & 1; S = 2; }
    else                { qbb = 43 - slot; seg = 0; S = 1; }

    const int ns = 2 * qbb + 2;  // 64-key steps for this 128q block
    const int sb0 = seg * ns / S;
    const int sb1 = (seg + 1) * ns / S;

    // staging (verbatim v9): unit u = wv*2+i covers rows u*8..u*8+7.
    // lane -> row u*8 + (lane>>3), phys 16B slot lane&7; source col
    // pre-swizzled: logical slot = (lane&7) ^ (row&7).
    const int rr = lane >> 3;                  // 0..7
    const int scol = ((lane & 7) ^ rr) * 8;    // swizzled source col (shorts)

    const short* kptr[2];
    const short* vptr[2];
    short* kdst[2];
    short* vdst[2];
#pragma unroll
    for (int i = 0; i < 2; i++) {
        const int u = wv * 2 + i;
        kptr[i] = qkv + (size_t)(b * 2048 + sb0 * 64 + u * 8 + rr) * 3072 + 1024 +
                  h * 64 + scol;
        kdst[i] = &Ks[0][(u * 8) * 64];
        vptr[i] = VtG + ((size_t)bh * 64 + u * 8 + rr) * 2048 + sb0 * 64 + scol;
        vdst[i] = &Vt[0][(u * 8) * 64];
    }
    const int bufoff = 64 * 64;  // shorts
    const int buf0 = sb0 & 1;

    // ---- prologue: K/V(sb0) -> buf0; Q -> regs (global, once) ----
#pragma unroll
    for (int i = 0; i < 2; i++) {
        async_copy16(kptr[i], kdst[i] + buf0 * bufoff);
        async_copy16(vptr[i], vdst[i] + buf0 * bufoff);
        kptr[i] += 64 * 3072;
        vptr[i] += 64;
    }
    short8 qf[2][2];
    {
        const short* qbase = qkv +
            (size_t)(b * 2048 + qbb * 128 + wv * 32 + l16) * 3072 + h * 64 + quad * 8;
#pragma unroll
        for (int qt = 0; qt < 2; qt++)
#pragma unroll
            for (int hf = 0; hf < 2; hf++)
                qf[qt][hf] = *(const short8*)(qbase + qt * 16 * 3072 + hf * 32);
    }
    __syncthreads();  // drain prologue loads

    // read-side swizzled slot (constant per lane): quad ^ (row&7), row&7=l16&7
    const int sl = (quad ^ (l16 & 7)) * 8;

    const f32x4 minit = {-17.3123405f, -17.3123405f, -17.3123405f, -17.3123405f};
    f32x4 O[2][4];
#pragma unroll
    for (int qt = 0; qt < 2; qt++)
#pragma unroll
        for (int dt = 0; dt < 4; dt++) O[qt][dt] = {0.f, 0.f, 0.f, 0.f};
    float lp[2] = {0.f, 0.f};
    const int qmin = qbb * 128 + wv * 32;  // wave's lowest q row

    for (int sb = sb0; sb < sb1; sb++) {
        const int cur = sb & 1;
        if (sb != sb0) __syncthreads();  // drains prefetch into cur; frees other buf
        if (sb + 1 < sb1) {
            const int nxt = cur ^ 1;
#pragma unroll
            for (int i = 0; i < 2; i++) {
                async_copy16(kptr[i], kdst[i] + nxt * bufoff);
                async_copy16(vptr[i], vdst[i] + nxt * bufoff);
                kptr[i] += 64 * 3072;
                vptr[i] += 64;
            }
        }
        const short* Kc = &Ks[cur][0];
        const short* Vc = &Vt[cur][0];
        const bool needmask = (sb * 64 + 63 > qmin);  // wave-uniform

        // ---- per 32-key chunk c (v9's wvk role): K/V frags, QK^T, P, PV ----
#pragma unroll
        for (int c = 0; c < 2; c++) {
            short8 kf0[2], kf1[2], vf[4];
#pragma unroll
            for (int hf = 0; hf < 2; hf++) {
                kf0[hf] = *(const short8*)
                    &Kc[((2 * c) * 16 + l16) * 64 + (sl ^ (hf << 5))];
                kf1[hf] = *(const short8*)
                    &Kc[((2 * c + 1) * 16 + l16) * 64 + (sl ^ (hf << 5))];
            }
#pragma unroll
            for (int dt = 0; dt < 4; dt++)
                vf[dt] = *(const short8*)
                    &Vc[(dt * 16 + l16) * 64 + (sl ^ (c << 5))];

#pragma unroll
            for (int qt = 0; qt < 2; qt++) {
                f32x4 sA = __builtin_amdgcn_mfma_f32_16x16x32_bf16(kf0[0], qf[qt][0], minit, 0, 0, 0);
                sA = __builtin_amdgcn_mfma_f32_16x16x32_bf16(kf0[1], qf[qt][1], sA, 0, 0, 0);
                f32x4 sB = __builtin_amdgcn_mfma_f32_16x16x32_bf16(kf1[0], qf[qt][0], minit, 0, 0, 0);
                sB = __builtin_amdgcn_mfma_f32_16x16x32_bf16(kf1[1], qf[qt][1], sB, 0, 0, 0);
                if (needmask) {  // causal
                    const int qcol = qmin + qt * 16 + l16;
                    const int key0 = sb * 64 + c * 32 + quad * 4;
#pragma unroll
                    for (int r = 0; r < 4; r++) {
                        if (key0 + r > qcol) sA[r] = -1e30f;
                        if (key0 + 16 + r > qcol) sB[r] = -1e30f;
                    }
                }
                union { u32x4 u; short8 s; } pa;
#pragma unroll
                for (int t = 0; t < 4; t++) {
                    sA[t] = __builtin_amdgcn_exp2f(sA[t]);
                    sB[t] = __builtin_amdgcn_exp2f(sB[t]);
                    lp[qt] += sA[t] + sB[t];
                    pa.u[t] = pack_bf16x2(sA[t], sB[t]);
                }
                __builtin_amdgcn_s_setprio(1);
#pragma unroll
                for (int dt = 0; dt < 4; dt++)
                    O[qt][dt] = __builtin_amdgcn_mfma_f32_16x16x32_bf16(
                        pa.s, vf[dt], O[qt][dt], 0, 0, 0);
                __builtin_amdgcn_s_setprio(0);
            }
        }
    }

    // ---- l: reduce over quads (keys), transpose within wave via lred ----
#pragma unroll
    for (int qt = 0; qt < 2; qt++) {
        float v = lp[qt];
        v += __shfl_xor(v, 16);
        v += __shfl_xor(v, 32);
        if (quad == 0) lred[wv][qt * 16 + l16] = v;  // wave-local, no barrier
    }

    // ---- output: each wave writes its own 32 q rows ----
    if (S == 1) {
#pragma unroll
        for (int qt = 0; qt < 2; qt++)
#pragma unroll
            for (int r = 0; r < 4; r++) {
                const int q = wv * 32 + qt * 16 + quad * 4 + r;
                const float inv = 1.f / lred[wv][qt * 16 + quad * 4 + r];
#pragma unroll
                for (int dt = 0; dt < 4; dt++)
                    Yg[(size_t)(b * 2048 + qbb * 128 + q) * 1024 + h * 64 +
                       dt * 16 + l16] = (short)f2bfbits(O[qt][dt][r] * inv);
            }
    } else {
        const int qidx = qbb - 4;  // 0..11
        const int base = ((seg * 32 + bh) * 12 + qidx) * 128;
#pragma unroll
        for (int qt = 0; qt < 2; qt++)
#pragma unroll
            for (int r = 0; r < 4; r++) {
                const int q = wv * 32 + qt * 16 + quad * 4 + r;
#pragma unroll
                for (int dt = 0; dt < 4; dt++)
                    Opart[(size_t)(base + q) * 64 + dt * 16 + l16] =
                        (short)f2bfbits(O[qt][dt][r]);  // unnormalized
                if (l16 == 0) ml[base + q] = lred[wv][qt * 16 + quad * 4 + r];
            }
    }
}

// ---------------------------------------------------------------------------
// Combine split-K partials: S=4 for qbb>=8, S=2 for qbb in [4,8).
// grid.x = 24: qbb = 4 + (x>>1), 64-row half = x&1.
// ---------------------------------------------------------------------------
__global__ __launch_bounds__(256) void attn_combine11(
    const short* __restrict__ Opart, const float* __restrict__ ml,
    short* __restrict__ Yg) {
    const int x = blockIdx.x;
    const int qbb = 4 + (x >> 1);
    const int half = x & 1;
    const int bh = blockIdx.y;
    const int b = bh >> 4, h = bh & 15;
    const int S = (qbb >= 8) ? 4 : 2;
    const int qidx = qbb - 4;
    const int tid = threadIdx.x;
    const int q = (tid >> 2) + half * 64;  // row within 128q block
    const int d0 = (tid & 3) * 16;

    float a0[8] = {}, a1[8] = {};
    float lsum = 0.f;
    for (int s = 0; s < S; s++) {
        const int idx = ((s * 32 + bh) * 12 + qidx) * 128 + q;
        lsum += ml[idx];
        const short* p = Opart + (size_t)idx * 64 + d0;
        short8 x0 = *(const short8*)p;
        short8 x1 = *(const short8*)(p + 8);
#pragma unroll
        for (int t = 0; t < 8; t++) {
            a0[t] += bfbits2f((unsigned short)x0[t]);
            a1[t] += bfbits2f((unsigned short)x1[t]);
        }
    }
    const float inv = 1.f / lsum;
    short8 o0, o1;
#pragma unroll
    for (int t = 0; t < 8; t++) {
        o0[t] = (short)f2bfbits(a0[t] * inv);
        o1[t] = (short)f2bfbits(a1[t] * inv);
    }
    short* yp = Yg + (size_t)(b * 2048 + qbb * 128 + q) * 1024 + h * 64 + d0;
    *(short8*)yp = o0;
    *(short8*)(yp + 8) = o1;
}

// ---------------------------------------------------------------------------
extern "C" void kernel_launch(void* const* d_in, const int* in_sizes, int n_in,
                              void* d_out, int out_size, void* d_ws, size_t ws_size,
                              hipStream_t stream) {
    const int M = 2 * 2048;
    const int D = 1024;

    // ws: xb/y 8M | WT 8M | qkv 24M | VtG 8M | Opart 24M | ml 0.75M  (~73 MiB)
    char* w = (char*)d_ws;
    short* xb  = (short*)w;
    short* WqT = (short*)(w + (8u << 20));
    short* WkT = WqT + (1u << 20);
    short* WvT = WkT + (1u << 20);
    short* WoT = WvT + (1u << 20);
    short* qkv = WoT + (1u << 20);            // [4096][3072] (V region unused)
    short* VtG = qkv + (size_t)M * 3072;      // [32*64][2048] pi-interleaved
    short* Opart = VtG + (size_t)2048 * 2048; // [4][32][12][128][64] bf16
    float* mlp = (float*)(Opart + (size_t)4 * 32 * 12 * 128 * 64);
    short* y = xb;  // alias: xb dead after QKV GEMM

    prep<<<6144, 256, 0, stream>>>(d_in[0], d_in[1], d_in[2], d_in[3], d_in[4],
                                   xb, WqT, WkT, WvT, WoT);

    // QKV GEMM with fused V transpose: V blocks (n0>=2048) write VtG directly.
    gemm_async<128><<<dim3(3072 / 128, M / 128), 256, 0, stream>>>(
        xb, WqT, qkv, nullptr, VtG, M, 3072, D);

    attn_mfma12<<<dim3(32, 44), 256, 0, stream>>>(qkv, VtG, y, Opart, mlp);
    attn_combine11<<<dim3(24, 32), 256, 0, stream>>>(Opart, mlp, y);

    gemm_async<64><<<dim3(D / 64, M / 128), 256, 0, stream>>>(
        y, WoT, d_out, (const unsigned int*)d_in[0], nullptr, M, D, D);
}

// Round 10
// 180.108 us; speedup vs baseline: 2.1664x; 1.0024x over previous
//
#include <hip/hip_runtime.h>
#include <hip/hip_bf16.h>

typedef __hip_bfloat16 bf16;
typedef __attribute__((ext_vector_type(8))) short short8;
typedef __attribute__((ext_vector_type(4))) float f32x4;
typedef __attribute__((ext_vector_type(4))) unsigned int u32x4;

__device__ __forceinline__ float bfbits2f(unsigned short u) {
    return __uint_as_float(((unsigned int)u) << 16);
}
__device__ __forceinline__ unsigned short f2bfbits(float f) {
    union { float f; unsigned int u; } x;
    x.f = f;
    unsigned int r = x.u + 0x7FFFu + ((x.u >> 16) & 1u);
    return (unsigned short)(r >> 16);
}
// pack two fp32 -> two bf16 in one dword
__device__ __forceinline__ unsigned int pack_bf16x2(float lo, float hi) {
    unsigned int u0 = __float_as_uint(lo) + 0x8000u;
    unsigned int u1 = __float_as_uint(hi) + 0x8000u;
    return __builtin_amdgcn_perm(u1, u0, 0x07060302u);
}
// async 16B global->LDS (wave-uniform LDS base; HW adds lane*16)
__device__ __forceinline__ void async_copy16(const void* g, void* l) {
    __builtin_amdgcn_global_load_lds(
        (const __attribute__((address_space(1))) void*)g,
        (__attribute__((address_space(3))) void*)l, 16, 0, 0);
}
// wave-level dtype sniff: true if the 64 dwords at p have bf16-plausible
// low halves (bf16 tensor), false for fp32 (low half = mantissa noise).
__device__ __forceinline__ bool sniff_bf16(const unsigned int* p, int lane) {
    unsigned int wd = p[lane];
    unsigned int e = (wd >> 7) & 0xFFu;
    return __popcll(__ballot(e >= 90u && e <= 150u)) > 40;
}

// ---------------------------------------------------------------------------
// prep: fused x-conversion (blocks 0..2047) + weight transpose/convert
// (blocks 2048..6143). Per-block inline dtype detection (no flags kernel).
// Wq pre-scaled by 0.125 * log2(e) so attention can use raw v_exp_f32 (2^x).
// ---------------------------------------------------------------------------
__global__ __launch_bounds__(256) void prep(
    const void* __restrict__ X, const void* __restrict__ W1,
    const void* __restrict__ W2, const void* __restrict__ W3,
    const void* __restrict__ W4, short* __restrict__ xb,
    short* __restrict__ O1, short* __restrict__ O2,
    short* __restrict__ O3, short* __restrict__ O4) {
    __shared__ float tbuf[32][33];
    const int bx = blockIdx.x;
    const int tid = threadIdx.x;
    const int lane = tid & 63;

    if (bx < 2048) {
        const bool isBf = sniff_bf16((const unsigned int*)X, lane);
        const int i = (bx * 256 + tid) * 8;
        if (isBf) {
            *(short8*)&xb[i] = *(const short8*)((const short*)X + i);
        } else {
            const float* xf = (const float*)X + i;
            float4 a = *(const float4*)xf;
            float4 b = *(const float4*)(xf + 4);
            short8 o;
            o[0] = (short)f2bfbits(a.x); o[1] = (short)f2bfbits(a.y);
            o[2] = (short)f2bfbits(a.z); o[3] = (short)f2bfbits(a.w);
            o[4] = (short)f2bfbits(b.x); o[5] = (short)f2bfbits(b.y);
            o[6] = (short)f2bfbits(b.z); o[7] = (short)f2bfbits(b.w);
            *(short8*)&xb[i] = o;
        }
    } else {
        const void* Ws[4] = {W1, W2, W3, W4};
        short* Os[4] = {O1, O2, O3, O4};
        const int t = bx - 2048;
        const int wsel = t >> 10;
        const int tile = t & 1023;
        const int bxt = tile & 31, byt = tile >> 5;
        const void* W = Ws[wsel];
        const bool isBf = sniff_bf16((const unsigned int*)W, lane);
        // 0.125 * log2(e): scores come out pre-scaled for exp2-based softmax
        const float scale = (wsel == 0) ? 0.18033688f : 1.0f;
        short* O = Os[wsel];

        const int tx = tid & 31, ty = tid >> 5;
        const int gx = bxt * 32 + tx;
#pragma unroll
        for (int i = 0; i < 4; i++) {
            const int gy = byt * 32 + ty + i * 8;
            float v = isBf
                ? bfbits2f(((const unsigned short*)W)[(size_t)gy * 1024 + gx])
                : ((const float*)W)[(size_t)gy * 1024 + gx];
            tbuf[ty + i * 8][tx] = v * scale;
        }
        __syncthreads();
#pragma unroll
        for (int i = 0; i < 4; i++) {
            const int orow = bxt * 32 + ty + i * 8;
            const int ocol = byt * 32 + tx;
            O[(size_t)orow * 1024 + ocol] = (short)f2bfbits(tbuf[tx][ty + i * 8]);
        }
    }
}

// ---------------------------------------------------------------------------
// MFMA GEMM, single-barrier dbuf K-loop. xdet==nullptr -> bf16 out;
// else output dtype follows sniffed dtype of xdet (the original x tensor).
// T2 XOR swizzle via pre-swizzled global source (rule #21).
// VtGp != nullptr (QKV call only, BN=128): blocks with n0 >= 2048 are pure-V
// blocks; their epilogue writes pi-interleaved VtG directly (fused
// transpose_v) and skips the qkv V region entirely.
// pi(l) within 32-token blocks: pl = (l & ~31) + 2*(l&15) + ((l>>4)&1).
// ---------------------------------------------------------------------------
template <int BN>
__global__ __launch_bounds__(256) void gemm_async(const short* __restrict__ A,
                                                  const short* __restrict__ Bt,
                                                  void* __restrict__ C,
                                                  const unsigned int* __restrict__ xdet,
                                                  short* __restrict__ VtGp,
                                                  int M, int N, int K) {
    __shared__ short As[2][128 * 32];
    __shared__ short Bs[2][BN * 32];
    constexpr int NI = BN / 32;

    const int tid = threadIdx.x;
    const int lane = tid & 63;
    const int wv = __builtin_amdgcn_readfirstlane(tid >> 6);
    const int quad = lane >> 4, l16 = lane & 15;
    const int wr = wv >> 1, wc = wv & 1;
    const int m0 = blockIdx.y * 128, n0 = blockIdx.x * BN;

    const int gr = lane >> 2;                               // staged row in 16-row unit
    const int gc = ((lane & 3) ^ ((lane >> 3) & 3)) * 8;    // pre-swizzled source col

    const f32x4 zero = {0.f, 0.f, 0.f, 0.f};
    f32x4 acc[4][NI];
#pragma unroll
    for (int mi = 0; mi < 4; mi++)
#pragma unroll
        for (int ni = 0; ni < NI; ni++) acc[mi][ni] = zero;

    const short* aptr[2];
    const short* bptr[BN / 64];
#pragma unroll
    for (int t = 0; t < 2; t++)
        aptr[t] = A + (size_t)(m0 + t * 64 + wv * 16 + gr) * K + gc;
#pragma unroll
    for (int t = 0; t < BN / 64; t++)
        bptr[t] = Bt + (size_t)(n0 + t * 64 + wv * 16 + gr) * K + gc;

#pragma unroll
    for (int t = 0; t < 2; t++) async_copy16(aptr[t], &As[0][(t * 64 + wv * 16) * 32]);
#pragma unroll
    for (int t = 0; t < BN / 64; t++) async_copy16(bptr[t], &Bs[0][(t * 64 + wv * 16) * 32]);

    // read-side swizzled 16B slot (constant per lane): quad ^ ((row>>1)&3)
    const int ss = (quad ^ ((l16 >> 1) & 3)) * 8;

    for (int k0 = 0; k0 < K; k0 += 32) {
        const int cur = (k0 >> 5) & 1;
        __syncthreads();
        if (k0 + 32 < K) {
            const int nxt = cur ^ 1;
#pragma unroll
            for (int t = 0; t < 2; t++)
                async_copy16(aptr[t] + k0 + 32, &As[nxt][(t * 64 + wv * 16) * 32]);
#pragma unroll
            for (int t = 0; t < BN / 64; t++)
                async_copy16(bptr[t] + k0 + 32, &Bs[nxt][(t * 64 + wv * 16) * 32]);
        }

        short8 af[4], bfv[NI];
#pragma unroll
        for (int mi = 0; mi < 4; mi++)
            af[mi] = *(const short8*)&As[cur][(wr * 64 + mi * 16 + l16) * 32 + ss];
#pragma unroll
        for (int ni = 0; ni < NI; ni++)
            bfv[ni] = *(const short8*)&Bs[cur][(wc * (BN / 2) + ni * 16 + l16) * 32 + ss];
#pragma unroll
        for (int mi = 0; mi < 4; mi++)
#pragma unroll
            for (int ni = 0; ni < NI; ni++)
                acc[mi][ni] = __builtin_amdgcn_mfma_f32_16x16x32_bf16(
                    af[mi], bfv[ni], acc[mi][ni], 0, 0, 0);
    }

    if (VtGp != nullptr && n0 >= 2048) {
        // fused V transpose: scatter into pi-interleaved VtG (skip qkv)
        unsigned short* Vw = (unsigned short*)VtGp;
#pragma unroll
        for (int mi = 0; mi < 4; mi++)
#pragma unroll
            for (int ni = 0; ni < NI; ni++)
#pragma unroll
                for (int r = 0; r < 4; r++) {
                    const int row = m0 + wr * 64 + mi * 16 + quad * 4 + r;
                    const int col = n0 + wc * (BN / 2) + ni * 16 + l16;
                    const int vcol = col - 2048;
                    const int hh = vcol >> 6, d = vcol & 63;
                    const int bb = row >> 11, lloc = row & 2047;
                    const int pl = (lloc & ~31) + 2 * (lloc & 15) + ((lloc >> 4) & 1);
                    Vw[((size_t)(bb * 16 + hh) * 64 + d) * 2048 + pl] =
                        f2bfbits(acc[mi][ni][r]);
                }
        return;
    }

    bool outBf = true;
    if (xdet) outBf = sniff_bf16(xdet, lane);
    if (outBf) {
        unsigned short* Cb = (unsigned short*)C;
#pragma unroll
        for (int mi = 0; mi < 4; mi++)
#pragma unroll
            for (int ni = 0; ni < NI; ni++)
#pragma unroll
                for (int r = 0; r < 4; r++) {
                    const int row = m0 + wr * 64 + mi * 16 + quad * 4 + r;
                    const int col = n0 + wc * (BN / 2) + ni * 16 + l16;
                    Cb[(size_t)row * N + col] = f2bfbits(acc[mi][ni][r]);
                }
    } else {
        float* Cf = (float*)C;
#pragma unroll
        for (int mi = 0; mi < 4; mi++)
#pragma unroll
            for (int ni = 0; ni < NI; ni++)
#pragma unroll
                for (int r = 0; r < 4; r++) {
                    const int row = m0 + wr * 64 + mi * 16 + quad * 4 + r;
                    const int col = n0 + wc * (BN / 2) + ni * 16 + l16;
                    Cf[(size_t)row * N + col] = acc[mi][ni][r];
                }
    }
}

// ---------------------------------------------------------------------------
// MFMA flash attention v13 = v12 compute (verbatim) + longest-first slot
// dispatch. Diagnosis: every variant (v7/v9/v10/v12) landed at 43-45us with
// max-8-step blocks; occupancy 23% => per-block step latency ~5.6k cyc, so
// an 8-step block is ~19us of critical path. The old order dispatched some
// 8-step slots (qbb7 S=2, qbb3 S=1) LAST -> they started ~20us in and set
// the 43us makespan. v13 maps blockIdx.y through a table sorted by
// descending step count (LPT schedule): 8-step slots first, 2-step last.
// Same (qbb,seg,S) set as v12 -> bit-identical outputs.
// steps/slot: S=4 qbb15:{8888} 14:{7878} 13:{7777} 12:{6767} 11:{6666}
// 10:{5656} 9:{5555} 8:{4545}; S=2 qbb7:{88} 6:{77} 5:{66} 4:{55};
// S=1 qbb3:8 2:6 1:4 0:2.
// ---------------------------------------------------------------------------
__global__ __launch_bounds__(256, 4) void attn_mfma13(
    const short* __restrict__ qkv, const short* __restrict__ VtG,
    short* __restrict__ Yg, short* __restrict__ Opart, float* __restrict__ ml) {
    __shared__ short Ks[2][64 * 64];   // [buf][key][64 d] swizzled, 8KB/buf
    __shared__ short Vt[2][64 * 64];   // [buf][d][64 key pi] swizzled
    __shared__ float lred[4][32];      // [wave][q] wave-local l transpose

    // longest-first slot table (44 entries), sorted by steps desc:
    // 8: 15/0,15/1,15/2,15/3,14/1,14/3,7s2/0,7s2/1,3s1
    // 7: 14/0,14/2,13/0..3,12/1,12/3,6s2/0,6s2/1
    // 6: 12/0,12/2,11/0..3,10/1,10/3,5s2/0,5s2/1,2s1
    // 5: 10/0,10/2,9/0..3,8/1,8/3,4s2/0,4s2/1
    // 4: 8/0,8/2,1s1   2: 0s1
    static const unsigned char qbbT[44] = {
        15,15,15,15,14,14, 7, 7, 3,
        14,14,13,13,13,13,12,12, 6, 6,
        12,12,11,11,11,11,10,10, 5, 5, 2,
        10,10, 9, 9, 9, 9, 8, 8, 4, 4,
         8, 8, 1, 0};
    static const unsigned char segT[44] = {
         0, 1, 2, 3, 1, 3, 0, 1, 0,
         0, 2, 0, 1, 2, 3, 1, 3, 0, 1,
         0, 2, 0, 1, 2, 3, 1, 3, 0, 1, 0,
         0, 2, 0, 1, 2, 3, 1, 3, 0, 1,
         0, 2, 0, 0};
    static const unsigned char ST[44] = {
         4, 4, 4, 4, 4, 4, 2, 2, 1,
         4, 4, 4, 4, 4, 4, 4, 4, 2, 2,
         4, 4, 4, 4, 4, 4, 4, 4, 2, 2, 1,
         4, 4, 4, 4, 4, 4, 4, 4, 2, 2,
         4, 4, 1, 1};

    const int tid = threadIdx.x;
    const int lane = tid & 63;
    const int wv = __builtin_amdgcn_readfirstlane(tid >> 6);  // 0..3 = q strip
    const int quad = lane >> 4, l16 = lane & 15;
    const int bh = blockIdx.x;  // bh fastest: 32 blocks per slot dispatch together
    const int b = bh >> 4, h = bh & 15;

    const int slot = blockIdx.y;
    const int qbb = qbbT[slot];
    const int seg = segT[slot];
    const int S = ST[slot];

    const int ns = 2 * qbb + 2;  // 64-key steps for this 128q block
    const int sb0 = seg * ns / S;
    const int sb1 = (seg + 1) * ns / S;

    // staging (verbatim v9): unit u = wv*2+i covers rows u*8..u*8+7.
    // lane -> row u*8 + (lane>>3), phys 16B slot lane&7; source col
    // pre-swizzled: logical slot = (lane&7) ^ (row&7).
    const int rr = lane >> 3;                  // 0..7
    const int scol = ((lane & 7) ^ rr) * 8;    // swizzled source col (shorts)

    const short* kptr[2];
    const short* vptr[2];
    short* kdst[2];
    short* vdst[2];
#pragma unroll
    for (int i = 0; i < 2; i++) {
        const int u = wv * 2 + i;
        kptr[i] = qkv + (size_t)(b * 2048 + sb0 * 64 + u * 8 + rr) * 3072 + 1024 +
                  h * 64 + scol;
        kdst[i] = &Ks[0][(u * 8) * 64];
        vptr[i] = VtG + ((size_t)bh * 64 + u * 8 + rr) * 2048 + sb0 * 64 + scol;
        vdst[i] = &Vt[0][(u * 8) * 64];
    }
    const int bufoff = 64 * 64;  // shorts
    const int buf0 = sb0 & 1;

    // ---- prologue: K/V(sb0) -> buf0; Q -> regs (global, once) ----
#pragma unroll
    for (int i = 0; i < 2; i++) {
        async_copy16(kptr[i], kdst[i] + buf0 * bufoff);
        async_copy16(vptr[i], vdst[i] + buf0 * bufoff);
        kptr[i] += 64 * 3072;
        vptr[i] += 64;
    }
    short8 qf[2][2];
    {
        const short* qbase = qkv +
            (size_t)(b * 2048 + qbb * 128 + wv * 32 + l16) * 3072 + h * 64 + quad * 8;
#pragma unroll
        for (int qt = 0; qt < 2; qt++)
#pragma unroll
            for (int hf = 0; hf < 2; hf++)
                qf[qt][hf] = *(const short8*)(qbase + qt * 16 * 3072 + hf * 32);
    }
    __syncthreads();  // drain prologue loads

    // read-side swizzled slot (constant per lane): quad ^ (row&7), row&7=l16&7
    const int sl = (quad ^ (l16 & 7)) * 8;

    const f32x4 minit = {-17.3123405f, -17.3123405f, -17.3123405f, -17.3123405f};
    f32x4 O[2][4];
#pragma unroll
    for (int qt = 0; qt < 2; qt++)
#pragma unroll
        for (int dt = 0; dt < 4; dt++) O[qt][dt] = {0.f, 0.f, 0.f, 0.f};
    float lp[2] = {0.f, 0.f};
    const int qmin = qbb * 128 + wv * 32;  // wave's lowest q row

    for (int sb = sb0; sb < sb1; sb++) {
        const int cur = sb & 1;
        if (sb != sb0) __syncthreads();  // drains prefetch into cur; frees other buf
        if (sb + 1 < sb1) {
            const int nxt = cur ^ 1;
#pragma unroll
            for (int i = 0; i < 2; i++) {
                async_copy16(kptr[i], kdst[i] + nxt * bufoff);
                async_copy16(vptr[i], vdst[i] + nxt * bufoff);
                kptr[i] += 64 * 3072;
                vptr[i] += 64;
            }
        }
        const short* Kc = &Ks[cur][0];
        const short* Vc = &Vt[cur][0];
        const bool needmask = (sb * 64 + 63 > qmin);  // wave-uniform

        // ---- per 32-key chunk c (v9's wvk role): K/V frags, QK^T, P, PV ----
#pragma unroll
        for (int c = 0; c < 2; c++) {
            short8 kf0[2], kf1[2], vf[4];
#pragma unroll
            for (int hf = 0; hf < 2; hf++) {
                kf0[hf] = *(const short8*)
                    &Kc[((2 * c) * 16 + l16) * 64 + (sl ^ (hf << 5))];
                kf1[hf] = *(const short8*)
                    &Kc[((2 * c + 1) * 16 + l16) * 64 + (sl ^ (hf << 5))];
            }
#pragma unroll
            for (int dt = 0; dt < 4; dt++)
                vf[dt] = *(const short8*)
                    &Vc[(dt * 16 + l16) * 64 + (sl ^ (c << 5))];

#pragma unroll
            for (int qt = 0; qt < 2; qt++) {
                f32x4 sA = __builtin_amdgcn_mfma_f32_16x16x32_bf16(kf0[0], qf[qt][0], minit, 0, 0, 0);
                sA = __builtin_amdgcn_mfma_f32_16x16x32_bf16(kf0[1], qf[qt][1], sA, 0, 0, 0);
                f32x4 sB = __builtin_amdgcn_mfma_f32_16x16x32_bf16(kf1[0], qf[qt][0], minit, 0, 0, 0);
                sB = __builtin_amdgcn_mfma_f32_16x16x32_bf16(kf1[1], qf[qt][1], sB, 0, 0, 0);
                if (needmask) {  // causal
                    const int qcol = qmin + qt * 16 + l16;
                    const int key0 = sb * 64 + c * 32 + quad * 4;
#pragma unroll
                    for (int r = 0; r < 4; r++) {
                        if (key0 + r > qcol) sA[r] = -1e30f;
                        if (key0 + 16 + r > qcol) sB[r] = -1e30f;
                    }
                }
                union { u32x4 u; short8 s; } pa;
#pragma unroll
                for (int t = 0; t < 4; t++) {
                    sA[t] = __builtin_amdgcn_exp2f(sA[t]);
                    sB[t] = __builtin_amdgcn_exp2f(sB[t]);
                    lp[qt] += sA[t] + sB[t];
                    pa.u[t] = pack_bf16x2(sA[t], sB[t]);
                }
                __builtin_amdgcn_s_setprio(1);
#pragma unroll
                for (int dt = 0; dt < 4; dt++)
                    O[qt][dt] = __builtin_amdgcn_mfma_f32_16x16x32_bf16(
                        pa.s, vf[dt], O[qt][dt], 0, 0, 0);
                __builtin_amdgcn_s_setprio(0);
            }
        }
    }

    // ---- l: reduce over quads (keys), transpose within wave via lred ----
#pragma unroll
    for (int qt = 0; qt < 2; qt++) {
        float v = lp[qt];
        v += __shfl_xor(v, 16);
        v += __shfl_xor(v, 32);
        if (quad == 0) lred[wv][qt * 16 + l16] = v;  // wave-local, no barrier
    }

    // ---- output: each wave writes its own 32 q rows ----
    if (S == 1) {
#pragma unroll
        for (int qt = 0; qt < 2; qt++)
#pragma unroll
            for (int r = 0; r < 4; r++) {
                const int q = wv * 32 + qt * 16 + quad * 4 + r;
                const float inv = 1.f / lred[wv][qt * 16 + quad * 4 + r];
#pragma unroll
                for (int dt = 0; dt < 4; dt++)
                    Yg[(size_t)(b * 2048 + qbb * 128 + q) * 1024 + h * 64 +
                       dt * 16 + l16] = (short)f2bfbits(O[qt][dt][r] * inv);
            }
    } else {
        const int qidx = qbb - 4;  // 0..11
        const int base = ((seg * 32 + bh) * 12 + qidx) * 128;
#pragma unroll
        for (int qt = 0; qt < 2; qt++)
#pragma unroll
            for (int r = 0; r < 4; r++) {
                const int q = wv * 32 + qt * 16 + quad * 4 + r;
#pragma unroll
                for (int dt = 0; dt < 4; dt++)
                    Opart[(size_t)(base + q) * 64 + dt * 16 + l16] =
                        (short)f2bfbits(O[qt][dt][r]);  // unnormalized
                if (l16 == 0) ml[base + q] = lred[wv][qt * 16 + quad * 4 + r];
            }
    }
}

// ---------------------------------------------------------------------------
// Combine split-K partials: S=4 for qbb>=8, S=2 for qbb in [4,8).
// grid.x = 24: qbb = 4 + (x>>1), 64-row half = x&1.
// ---------------------------------------------------------------------------
__global__ __launch_bounds__(256) void attn_combine11(
    const short* __restrict__ Opart, const float* __restrict__ ml,
    short* __restrict__ Yg) {
    const int x = blockIdx.x;
    const int qbb = 4 + (x >> 1);
    const int half = x & 1;
    const int bh = blockIdx.y;
    const int b = bh >> 4, h = bh & 15;
    const int S = (qbb >= 8) ? 4 : 2;
    const int qidx = qbb - 4;
    const int tid = threadIdx.x;
    const int q = (tid >> 2) + half * 64;  // row within 128q block
    const int d0 = (tid & 3) * 16;

    float a0[8] = {}, a1[8] = {};
    float lsum = 0.f;
    for (int s = 0; s < S; s++) {
        const int idx = ((s * 32 + bh) * 12 + qidx) * 128 + q;
        lsum += ml[idx];
        const short* p = Opart + (size_t)idx * 64 + d0;
        short8 x0 = *(const short8*)p;
        short8 x1 = *(const short8*)(p + 8);
#pragma unroll
        for (int t = 0; t < 8; t++) {
            a0[t] += bfbits2f((unsigned short)x0[t]);
            a1[t] += bfbits2f((unsigned short)x1[t]);
        }
    }
    const float inv = 1.f / lsum;
    short8 o0, o1;
#pragma unroll
    for (int t = 0; t < 8; t++) {
        o0[t] = (short)f2bfbits(a0[t] * inv);
        o1[t] = (short)f2bfbits(a1[t] * inv);
    }
    short* yp = Yg + (size_t)(b * 2048 + qbb * 128 + q) * 1024 + h * 64 + d0;
    *(short8*)yp = o0;
    *(short8*)(yp + 8) = o1;
}

// ---------------------------------------------------------------------------
extern "C" void kernel_launch(void* const* d_in, const int* in_sizes, int n_in,
                              void* d_out, int out_size, void* d_ws, size_t ws_size,
                              hipStream_t stream) {
    const int M = 2 * 2048;
    const int D = 1024;

    // ws: xb/y 8M | WT 8M | qkv 24M | VtG 8M | Opart 24M | ml 0.75M  (~73 MiB)
    char* w = (char*)d_ws;
    short* xb  = (short*)w;
    short* WqT = (short*)(w + (8u << 20));
    short* WkT = WqT + (1u << 20);
    short* WvT = WkT + (1u << 20);
    short* WoT = WvT + (1u << 20);
    short* qkv = WoT + (1u << 20);            // [4096][3072] (V region unused)
    short* VtG = qkv + (size_t)M * 3072;      // [32*64][2048] pi-interleaved
    short* Opart = VtG + (size_t)2048 * 2048; // [4][32][12][128][64] bf16
    float* mlp = (float*)(Opart + (size_t)4 * 32 * 12 * 128 * 64);
    short* y = xb;  // alias: xb dead after QKV GEMM

    prep<<<6144, 256, 0, stream>>>(d_in[0], d_in[1], d_in[2], d_in[3], d_in[4],
                                   xb, WqT, WkT, WvT, WoT);

    // QKV GEMM with fused V transpose: V blocks (n0>=2048) write VtG directly.
    gemm_async<128><<<dim3(3072 / 128, M / 128), 256, 0, stream>>>(
        xb, WqT, qkv, nullptr, VtG, M, 3072, D);

    attn_mfma13<<<dim3(32, 44), 256, 0, stream>>>(qkv, VtG, y, Opart, mlp);
    attn_combine11<<<dim3(24, 32), 256, 0, stream>>>(Opart, mlp, y);

    gemm_async<64><<<dim3(D / 64, M / 128), 256, 0, stream>>>(
        y, WoT, d_out, (const unsigned int*)d_in[0], nullptr, M, D, D);
}